// Round 10
// baseline (513.967 us; speedup 1.0000x reference)
//
#include <hip/hip_runtime.h>
#include <hip/hip_bf16.h>
#include <math.h>
#include <string.h>

#define B_ 128
#define L_ 128
#define N_ 6
#define FA_ 39
#define FB_ 10
#define D_ 200
#define MB_ 256
#define R_ 3
#define T_ 2
#define NEGV -9e8f
#define BL_ (B_*L_)        // 16384
#define G3D_ (3*D_)        // 600
#define FP32TAG 0x3F800000u
#define KP 416             // padded K for gate GEMM
#define NP 896             // legacy width (creg region sizing only)
#define NP2 1024           // gate-collocated B2t width: col = g*256 + d
#define KC 224             // padded K for ctx GEMM (7*32)
#define NC 256             // padded N for ctx GEMM

typedef __hip_bfloat16 bf16;
typedef __attribute__((ext_vector_type(8))) short short8;
typedef __attribute__((ext_vector_type(4))) float f32x4;

__device__ __forceinline__ float b2f(const bf16 x){ return __bfloat162float(x); }
__device__ __forceinline__ unsigned short f2b(float v){ bf16 t = __float2bfloat16(v); return *reinterpret_cast<unsigned short*>(&t); }
__device__ __forceinline__ float bu2f(unsigned short u){ unsigned x = ((unsigned)u)<<16; float f; memcpy(&f,&x,4); return f; }
__device__ __forceinline__ float lo2f(unsigned x){ unsigned y = x<<16; float f; memcpy(&f,&y,4); return f; }
__device__ __forceinline__ float hi2f(unsigned x){ unsigned y = x & 0xffff0000u; float f; memcpy(&f,&y,4); return f; }
__device__ __forceinline__ float lreluf(float x){ return x>=0.f ? x : 0.01f*x; }
__device__ __forceinline__ float eluf(float x){ return x>0.f ? x : expm1f(x); }
__device__ __forceinline__ float sigmf(float x){ return 1.f/(1.f+expf(-x)); }

#define NSEG 14
struct CvtArgs { const void* src[NSEG]; int ofs[NSEG+1]; };

#define PREPB_N (R_*NP2*KP)    // 1277952 (gate-collocated)
#define PREPW_N (R_*NC*KC)     // 172032
#define PREPM_N (D_*G3D_)      // 120000 (per matrix)
#define PREPG_N (2*PREPM_N)    // 240000 (WGi + WGh flat bf16)
#define PREPT_N 40000          // WmtT [d][k]
#define PREPE_N 80000          // WmeT [d][k0..399]
#define CONV_N 23989
#define XHPAD_N (BL_*16)       // 262144
#define CPAD_N (BL_*24)        // 393216 cur16 pad zero
#define AROWS (BL_ + B_*MB_)   // 49152
#define A_N (AROWS*64)         // 3145728
#define BI_N (448*64)          // 28672

struct PrepArgs {
    CvtArgs cvt;
    const void *Wih, *Whh, *Watt, *mWih, *mWhh, *Wmt, *Wme;
    const void *bond, *Wnei, *atom, *Watom;
    float* conv;
    unsigned short *B2t, *WatT, *WGi, *WGh, *WmtT, *WmeT, *XH, *A16, *Bi16, *cur16;
    const unsigned* amtag;
    int ew_total;
};

__device__ __forceinline__ float ldd(const void* p, size_t i, bool f32){
    return f32 ? ((const float*)p)[i] : b2f(((const bf16*)p)[i]);
}

// prologue elementwise: small-param convert + all weight repacks + XH/cur16 pad + A16/Bi16
__global__ void __launch_bounds__(256) k_prep(PrepArgs A){
    bool f32 = (*A.amtag == FP32TAG);
    int i = blockIdx.x*256 + (int)threadIdx.x;
    if (i >= A.ew_total) return;
    if (i < CONV_N){
        int s = 0;
        while (i >= A.cvt.ofs[s+1]) s++;
        A.conv[i] = ldd(A.cvt.src[s], i - A.cvt.ofs[s], f32);
        return;
    }
    int i2 = i - CONV_N;
    if (i2 < PREPB_N){
        // gate-collocated: col c = g*256 + n, n<200 real.
        // g0: rsum full (x:Wih_r, h:Whh_r); g1: zsum full; g2: gin (x only); g3: ghn (h only)
        int kk = i2 % KP;
        int rest = i2 / KP;
        int c = rest % NP2;
        int r = rest / NP2;
        int g = c >> 8, n = c & 255;
        float v = 0.f;
        if (n < 200){
            if (g <= 1){
                int j = g*200 + n;
                if (kk < 200) v = ldd(A.Wih, ((size_t)(r*G3D_ + j))*D_ + kk, f32);
                else if (kk < 400) v = ldd(A.Whh, ((size_t)(r*G3D_ + j))*D_ + (kk-200), f32);
            } else if (g == 2){
                if (kk < 200) v = ldd(A.Wih, ((size_t)(r*G3D_ + 400 + n))*D_ + kk, f32);
            } else {
                if (kk >= 200 && kk < 400) v = ldd(A.Whh, ((size_t)(r*G3D_ + 400 + n))*D_ + (kk-200), f32);
            }
        }
        A.B2t[i2] = f2b(v);
        return;
    }
    int i3 = i2 - PREPB_N;
    if (i3 < PREPW_N){
        int kk = i3 % KC;
        int rest = i3 / KC;
        int n = rest % NC;
        int r = rest / NC;
        float v = 0.f;
        if (kk < 200 && n < 200) v = ldd(A.Watt, ((size_t)r*D_ + kk)*D_ + n, f32);
        A.WatT[i3] = f2b(v);
        return;
    }
    int i4 = i3 - PREPW_N;
    if (i4 < PREPG_N){
        int half = i4 / PREPM_N;
        int s = i4 - half*PREPM_N;
        (half ? A.WGh : A.WGi)[s] = f2b(ldd(half ? A.mWhh : A.mWih, s, f32));
        return;
    }
    int i5 = i4 - PREPG_N;
    if (i5 < PREPT_N){
        int k = i5 / 200, d = i5 % 200;
        A.WmtT[(size_t)d*200 + k] = f2b(ldd(A.Wmt, i5, f32));
        return;
    }
    int i6 = i5 - PREPT_N;
    if (i6 < PREPE_N){
        int k = i6 / 200, d = i6 % 200;
        A.WmeT[(size_t)d*400 + k] = f2b(ldd(A.Wme, i6, f32));
        return;
    }
    int i7 = i6 - PREPE_N;
    if (i7 < XHPAD_N){
        int al = i7 >> 4, j = i7 & 15;
        A.XH[(size_t)al*KP + 400 + j] = 0;
        return;
    }
    int i7b = i7 - XHPAD_N;
    if (i7b < CPAD_N){
        int al = i7b / 24, j = i7b % 24;
        A.cur16[(size_t)al*KC + 200 + j] = 0;
        return;
    }
    int i8 = i7b - CPAD_N;
    if (i8 < A_N){
        int row = i8 >> 6, k = i8 & 63;
        float v = 0.f;
        if (row < BL_){
            if (k < FA_) v = ldd(A.atom, (size_t)row*FA_ + k, f32);
        } else {
            int rb = row - BL_;
            if (k >= FA_ && k < FA_+FB_) v = ldd(A.bond, (size_t)rb*FB_ + (k-FA_), f32);
        }
        A.A16[i8] = f2b(v);
        return;
    }
    int i9 = i8 - A_N;
    if (i9 < BI_N){
        int n = i9 >> 6, k = i9 & 63;
        float v = 0.f;
        if (n < 200){
            if (k < FA_) v = ldd(A.Watom, (size_t)k*D_ + n, f32);
        } else if (n < 400){
            if (k < FA_+FB_) v = ldd(A.Wnei, (size_t)k*D_ + (n-200), f32);
        }
        A.Bi16[i9] = f2b(v);
    }
}

// MFMA init GEMM: C[49152,448] = A16 @ Bi16^T. Atom rows -> XH h-half (lrelu+b_atom) and
// P16 (+b_nei); bond rows -> Q16. 128x64 tile, K=64 (2 steps).
__global__ void __launch_bounds__(256) k_initmm(const unsigned short* __restrict__ A16,
        const unsigned short* __restrict__ Bi16,
        const void* __restrict__ batom, const void* __restrict__ bnei,
        unsigned short* __restrict__ XH, unsigned short* __restrict__ P16,
        unsigned short* __restrict__ Q16, const unsigned* __restrict__ amtag){
    __shared__ unsigned short As[128][40];
    __shared__ unsigned short Bs[64][40];
    bool f32 = (*amtag == FP32TAG);
    int tid = threadIdx.x;
    int mt = (int)blockIdx.x / 7, nt = (int)blockIdx.x % 7;
    int m0 = mt*128, n0 = nt*64;
    if (m0 >= BL_ && n0 + 64 <= 200) return;   // bond rows x atom-feature cols: all dead
    int lane = tid & 63, wv = tid >> 6;
    int quad = lane >> 4, lm = lane & 15;
    f32x4 acc[2][4];
    #pragma unroll
    for (int a=0;a<2;a++)
        #pragma unroll
        for (int b=0;b<4;b++) acc[a][b] = (f32x4){0.f,0.f,0.f,0.f};
    for (int ks = 0; ks < 2; ks++){
        int r0_ = tid >> 2, c0 = (tid & 3) * 8;
        int r1_ = (tid + 256) >> 2, c1 = ((tid + 256) & 3) * 8;
        uint4 a0 = *(const uint4*)&A16[(size_t)(m0 + r0_)*64 + ks*32 + c0];
        uint4 a1 = *(const uint4*)&A16[(size_t)(m0 + r1_)*64 + ks*32 + c1];
        uint4 b0 = *(const uint4*)&Bi16[(size_t)(n0 + (tid >> 2))*64 + ks*32 + (tid & 3)*8];
        __syncthreads();
        *(uint4*)&As[r0_][c0] = a0;
        *(uint4*)&As[r1_][c1] = a1;
        *(uint4*)&Bs[tid >> 2][(tid & 3)*8] = b0;
        __syncthreads();
        short8 av0 = *(const short8*)&As[wv*32 + lm][quad*8];
        short8 av1 = *(const short8*)&As[wv*32 + 16 + lm][quad*8];
        #pragma unroll
        for (int ns=0; ns<4; ns++){
            short8 bv = *(const short8*)&Bs[ns*16 + lm][quad*8];
            acc[0][ns] = __builtin_amdgcn_mfma_f32_16x16x32_bf16(av0, bv, acc[0][ns], 0,0,0);
            acc[1][ns] = __builtin_amdgcn_mfma_f32_16x16x32_bf16(av1, bv, acc[1][ns], 0,0,0);
        }
    }
    #pragma unroll
    for (int ms=0; ms<2; ms++)
      #pragma unroll
      for (int ns=0; ns<4; ns++){
        int n = n0 + ns*16 + lm;
        #pragma unroll
        for (int i=0;i<4;i++){
            int row = m0 + wv*32 + ms*16 + quad*4 + i;
            float v = acc[ms][ns][i];
            if (row < BL_){
                if (n < 200){
                    XH[(size_t)row*KP + 200 + n] = f2b(lreluf(v + ldd(batom, n, f32)));
                } else if (n < 400){
                    P16[(size_t)row*D_ + (n-200)] = f2b(v + ldd(bnei, n-200, f32));
                }
            } else if (n >= 200 && n < 400){
                Q16[(size_t)(row-BL_)*D_ + (n-200)] = f2b(v);
            }
        }
      }
}

// attention (all rounds): softmax + weighted neighbor sum -> bf16 wnei (stride KC, zero pad).
__global__ void __launch_bounds__(256) k_attn(
        const unsigned short* __restrict__ cur16, const unsigned short* __restrict__ XH,
        const float* __restrict__ s1, const float* __restrict__ tb,
        const int* __restrict__ adl, const int* __restrict__ bdl,
        const unsigned short* __restrict__ P16, const unsigned short* __restrict__ Q16,
        const float* __restrict__ W_align, const float* __restrict__ b_align, int r,
        unsigned short* __restrict__ wnei, float* __restrict__ wsum){
    int bid = blockIdx.x;
    int mol = bid & (B_-1), chunk = bid >> 7;
    int wv = threadIdx.x >> 6, lane = threadIdx.x & 63;
    int al = mol*L_ + chunk*4 + wv;
    __shared__ float s_nei[4][N_][D_];

    int idxn[N_]; bool pad[N_];
    #pragma unroll
    for (int n=0;n<N_;n++){ idxn[n] = adl[al*N_ + n]; pad[n] = (idxn[n] == L_-1); }

    float s2[N_];
    float s1v;
    if (r == 0){
        const float* Wab = W_align + D_;
        float acc[N_+1];
        #pragma unroll
        for (int n=0;n<N_+1;n++) acc[n] = 0.f;
        #pragma unroll
        for (int n=0;n<N_;n++){
            int bd = bdl[al*N_ + n];
            const unsigned short* Prow = P16 + ((size_t)mol*L_ + idxn[n])*D_;
            const unsigned short* Qrow = Q16 + ((size_t)mol*MB_ + bd)*D_;
            for (int d=lane; d<D_; d+=64){
                float v = lreluf(bu2f(Prow[d]) + bu2f(Qrow[d]));
                s_nei[wv][n][d] = v;
                acc[n] += v * Wab[d];
            }
        }
        for (int d=lane; d<D_; d+=64)
            acc[N_] += bu2f(XH[(size_t)al*KP + 200 + d]) * W_align[d];
        #pragma unroll
        for (int o=32;o>0;o>>=1)
            #pragma unroll
            for (int n=0;n<N_+1;n++) acc[n] += __shfl_xor(acc[n],o);
        #pragma unroll
        for (int n=0;n<N_;n++) s2[n] = acc[n];
        s1v = acc[N_];
    } else {
        float tmp = 0.f;
        if (lane < N_) tmp = tb[mol*L_ + idxn[lane]];
        #pragma unroll
        for (int n=0;n<N_;n++) s2[n] = __shfl(tmp, n);
        s1v = s1[al];
    }

    float bav = b_align[r];
    float a[N_]; float mx = -1e30f;
    #pragma unroll
    for (int n=0;n<N_;n++){
        float v = lreluf(s1v + s2[n] + bav);
        if (pad[n]) v += NEGV;
        a[n] = v; mx = fmaxf(mx, v);
    }
    float w[N_]; float se = 0.f;
    #pragma unroll
    for (int n=0;n<N_;n++){ float e = expf(a[n]-mx); w[n]=e; se += e; }
    float inv = 1.f/se; float wsv = 0.f;
    #pragma unroll
    for (int n=0;n<N_;n++){ w[n] = pad[n] ? 0.f : w[n]*inv; wsv += w[n]; }

    if (r == 0){
        for (int d=lane; d<D_; d+=64){
            float acc = 0.f;
            #pragma unroll
            for (int n=0;n<N_;n++) acc += w[n] * s_nei[wv][n][d];
            wnei[(size_t)al*KC + d] = f2b(acc);
        }
    } else {
        for (int d=lane; d<D_; d+=64){
            float acc = 0.f;
            #pragma unroll
            for (int n=0;n<N_;n++) acc += w[n] * bu2f(cur16[((size_t)mol*L_ + idxn[n])*KC + d]);
            wnei[(size_t)al*KC + d] = f2b(acc);
        }
    }
    if (lane < 24) wnei[(size_t)al*KC + 200 + lane] = 0;
    if (lane==0) wsum[al] = wsv;
}

// MFMA ctx GEMM: elu(wnei[16384,KC] @ WatT[r]^T + wsum*bias) -> XH x-half. 128x64 tile.
// Prologue (n0==0 blocks): zero s1/tb (+curdot last round) for this round's gemm atomics,
// and zero XH pad cols 400-415 (ping-pong buffer may hold garbage there).
__global__ void __launch_bounds__(256) k_ctxmfma(const unsigned short* __restrict__ Wn,
        const float* __restrict__ wsum, const unsigned short* __restrict__ WatT,
        const float* __restrict__ bias, int r, unsigned short* __restrict__ XH,
        float* __restrict__ s1, float* __restrict__ tb, float* __restrict__ curdot){
    __shared__ unsigned short As[128][40];
    __shared__ unsigned short Bs[64][40];
    int tid = threadIdx.x;
    int m0 = ((int)blockIdx.x & 127) * 128;
    int n0 = ((int)blockIdx.x >> 7) * 64;
    if (n0 == 0 && tid < 128){
        int row = m0 + tid;
        s1[row] = 0.f; tb[row] = 0.f;
        if (r == R_-1) curdot[row] = 0.f;
        #pragma unroll
        for (int j=0;j<16;j++) XH[(size_t)row*KP + 400 + j] = 0;
    }
    const unsigned short* Bt = WatT + (size_t)r*NC*KC;
    int lane = tid & 63, wv = tid >> 6;
    int quad = lane >> 4, lm = lane & 15;
    f32x4 acc[2][4];
    #pragma unroll
    for (int a=0;a<2;a++)
        #pragma unroll
        for (int b=0;b<4;b++) acc[a][b] = (f32x4){0.f,0.f,0.f,0.f};
    for (int ks = 0; ks < 7; ks++){
        int r0_ = tid >> 2, c0 = (tid & 3) * 8;
        int r1_ = (tid + 256) >> 2, c1 = ((tid + 256) & 3) * 8;
        uint4 a0 = *(const uint4*)&Wn[(size_t)(m0 + r0_)*KC + ks*32 + c0];
        uint4 a1 = *(const uint4*)&Wn[(size_t)(m0 + r1_)*KC + ks*32 + c1];
        uint4 b0 = *(const uint4*)&Bt[(size_t)(n0 + (tid >> 2))*KC + ks*32 + (tid & 3)*8];
        __syncthreads();
        *(uint4*)&As[r0_][c0] = a0;
        *(uint4*)&As[r1_][c1] = a1;
        *(uint4*)&Bs[tid >> 2][(tid & 3)*8] = b0;
        __syncthreads();
        short8 av0 = *(const short8*)&As[wv*32 + lm][quad*8];
        short8 av1 = *(const short8*)&As[wv*32 + 16 + lm][quad*8];
        #pragma unroll
        for (int ns=0; ns<4; ns++){
            short8 bv = *(const short8*)&Bs[ns*16 + lm][quad*8];
            acc[0][ns] = __builtin_amdgcn_mfma_f32_16x16x32_bf16(av0, bv, acc[0][ns], 0,0,0);
            acc[1][ns] = __builtin_amdgcn_mfma_f32_16x16x32_bf16(av1, bv, acc[1][ns], 0,0,0);
        }
    }
    #pragma unroll
    for (int ms=0; ms<2; ms++)
      #pragma unroll
      for (int ns=0; ns<4; ns++){
        int n = n0 + ns*16 + lm;
        if (n < 200){
            float bv = bias[r*D_ + n];
            #pragma unroll
            for (int i=0;i<4;i++){
                int row = m0 + wv*32 + ms*16 + quad*4 + i;
                float v = acc[ms][ns][i] + wsum[row]*bv;
                XH[(size_t)row*KP + n] = f2b(eluf(v));
            }
        }
      }
}

// Fused gate GEMM + GRU, v3: 64 rows x 256 cols per block, grid = 256 m-tiles x 4 ds
// = 1024 blocks (~4 resident/CU, 16 waves -> latency hiding via TLP like old k_gemm's
// 896 blocks). Register prefetch pipeline: next K-step's 5 uint4 loads issue BEFORE the
// MFMAs of the current step (vmcnt wait lands at next LDS write, hidden under compute).
// bid: m = bid>>2, ds = bid&3 (adjacent blocks share the A panel -> L2 reuse).
// Wave wn owns dsub=wn; each thread holds all 4 gates for ONE (row,d): GRU in epilogue.
__global__ void __launch_bounds__(256, 3) k_gemm2(
        const unsigned short* __restrict__ XHr, unsigned short* __restrict__ XHw,
        const unsigned short* __restrict__ B2t, unsigned short* __restrict__ cur16,
        const float* __restrict__ bih, const float* __restrict__ bhh,
        const float* __restrict__ W_align, const float* __restrict__ Wma,
        float* __restrict__ s1, float* __restrict__ tb, float* __restrict__ curdot,
        int r){
    __shared__ unsigned short As[64][40];
    __shared__ unsigned short Bs[256][40];
    __shared__ float s_ab[4][64][2];
    int tid = threadIdx.x;
    int m0 = ((int)blockIdx.x >> 2) * 64;
    int ds = (int)blockIdx.x & 3;              // d-slice [ds*64, ds*64+64)
    const unsigned short* Bt = B2t + (size_t)r*NP2*KP;
    int lane = tid & 63, wn = tid >> 6;        // 4 waves = 4 dsub phases
    int quad = lane >> 4, lm = lane & 15;
    f32x4 acc[4][4];
    #pragma unroll
    for (int a=0;a<4;a++)
        #pragma unroll
        for (int b=0;b<4;b++) acc[a][b] = (f32x4){0.f,0.f,0.f,0.f};
    int ar = tid >> 2, ac = (tid & 3) * 8;     // ar in [0,64)
    // prefetch K-step 0
    uint4 pa = *(const uint4*)&XHr[(size_t)(m0 + ar)*KP + ac];
    uint4 pb[4];
    #pragma unroll
    for (int q=0;q<4;q++)
        pb[q] = *(const uint4*)&Bt[(size_t)(q*256 + ds*64 + ar)*KP + ac];
    for (int ks = 0; ks < 13; ks++){
        __syncthreads();                        // prior LDS reads done
        *(uint4*)&As[ar][ac] = pa;
        #pragma unroll
        for (int q=0;q<4;q++) *(uint4*)&Bs[q*64 + ar][ac] = pb[q];
        __syncthreads();
        if (ks < 12){                           // issue next-step loads under MFMA
            int ko = (ks+1)*32 + ac;
            pa = *(const uint4*)&XHr[(size_t)(m0 + ar)*KP + ko];
            #pragma unroll
            for (int q=0;q<4;q++)
                pb[q] = *(const uint4*)&Bt[(size_t)(q*256 + ds*64 + ar)*KP + ko];
        }
        short8 bv[4];
        #pragma unroll
        for (int g=0;g<4;g++) bv[g] = *(const short8*)&Bs[g*64 + wn*16 + lm][quad*8];
        #pragma unroll
        for (int mm=0; mm<4; mm++){
            short8 av = *(const short8*)&As[mm*16 + lm][quad*8];
            #pragma unroll
            for (int g=0;g<4;g++)
                acc[mm][g] = __builtin_amdgcn_mfma_f32_16x16x32_bf16(av, bv[g], acc[mm][g], 0,0,0);
        }
    }
    // ---- fused GRU epilogue: thread owns (rows: 4mm x quad4+i, single d) ----
    const float* bi = bih + r*G3D_;
    const float* bh = bhh + r*G3D_;
    const float* Wa = W_align + (r+1)*2*D_;    // dereferenced only when r<2
    bool last = (r == R_-1);
    int d = ds*64 + wn*16 + lm;
    bool dok = (d < 200);
    float bir=0.f,biz=0.f,bin=0.f,bhr=0.f,bhz=0.f,bhn=0.f,wa1=0.f,wa2=0.f;
    if (dok){
        bir=bi[d]; biz=bi[D_+d]; bin=bi[2*D_+d];
        bhr=bh[d]; bhz=bh[D_+d]; bhn=bh[2*D_+d];
        wa1 = last ? Wma[D_+d] : Wa[d];
        wa2 = last ? 0.f : Wa[D_+d];
    }
    #pragma unroll
    for (int mm=0; mm<4; mm++){
        float pa_[4] = {0.f,0.f,0.f,0.f}, pb_[4] = {0.f,0.f,0.f,0.f};
        if (dok){
            #pragma unroll
            for (int i=0;i<4;i++){
                int row = m0 + mm*16 + quad*4 + i;
                float rsum = acc[mm][0][i];
                float zsum = acc[mm][1][i];
                float gin  = acc[mm][2][i];
                float ghn  = acc[mm][3][i];
                float rr = sigmf(rsum + bir + bhr);
                float zz = sigmf(zsum + biz + bhz);
                float nn = tanhf(gin + bin + rr*(ghn + bhn));
                size_t hx = (size_t)row*KP + 200 + d;
                float hv = bu2f(XHr[hx]);
                float hn = (1.f-zz)*nn + zz*hv;
                XHw[hx] = f2b(hn);
                float cv = fmaxf(hn, 0.f);
                cur16[(size_t)row*KC + d] = f2b(cv);
                pa_[i] += cv * wa1;
                pb_[i] += cv * wa2;
            }
        }
        #pragma unroll
        for (int o=1;o<16;o<<=1){
            #pragma unroll
            for (int i=0;i<4;i++){ pa_[i] += __shfl_xor(pa_[i],o); pb_[i] += __shfl_xor(pb_[i],o); }
        }
        if (lm == 0){
            #pragma unroll
            for (int i=0;i<4;i++){
                int lr = mm*16 + quad*4 + i;
                s_ab[wn][lr][0] = pa_[i];
                s_ab[wn][lr][1] = pb_[i];
            }
        }
    }
    __syncthreads();
    if (tid < 64){
        int row = m0 + tid;
        float a1 = (s_ab[0][tid][0] + s_ab[1][tid][0]) + (s_ab[2][tid][0] + s_ab[3][tid][0]);
        float a2 = (s_ab[0][tid][1] + s_ab[1][tid][1]) + (s_ab[2][tid][1] + s_ab[3][tid][1]);
        if (last) atomicAdd(&curdot[row], a1);
        else { atomicAdd(&s1[row], a1); atomicAdd(&tb[row], a2); }
    }
}

__device__ __forceinline__ float brSum(float v, float* s_red){
    for (int o=32;o>0;o>>=1) v += __shfl_xor(v,o);
    int lane = threadIdx.x & 63, wid = threadIdx.x >> 6;
    __syncthreads();
    if (lane==0) s_red[wid] = v;
    __syncthreads();
    float r = 0.f;
    int nw = blockDim.x >> 6;
    for (int i=0;i<nw;i++) r += s_red[i];
    return r;
}

// 200-elem dot of a bf16 row (25x uint4) with an LDS f32 vector (16B-aligned)
__device__ __forceinline__ float dot200(const unsigned short* __restrict__ wrow,
                                        const float* __restrict__ v){
    const uint4* wp = (const uint4*)wrow;
    float a0=0.f, a1=0.f;
    #pragma unroll
    for (int kk=0; kk<25; kk++){
        uint4 u = wp[kk];
        f32x4 A = *(const f32x4*)&v[8*kk];
        f32x4 Bv = *(const f32x4*)&v[8*kk+4];
        a0 += A[0]*lo2f(u.x) + A[1]*hi2f(u.x);
        a1 += A[2]*lo2f(u.y) + A[3]*hi2f(u.y);
        a0 += Bv[0]*lo2f(u.z) + Bv[1]*hi2f(u.z);
        a1 += Bv[2]*lo2f(u.w) + Bv[3]*hi2f(u.w);
    }
    return a0 + a1;
}

// molecule phase, 512 threads (8 waves), phase-minimized (4 barriers/t-iter).
__global__ void __launch_bounds__(512, 1) k_mol(const unsigned short* __restrict__ cur16,
    const float* __restrict__ curdot, const float* __restrict__ atom_mask,
    const float* __restrict__ Wma, const float* __restrict__ bma,
    const unsigned short* __restrict__ WmtT, const float* __restrict__ bmt,
    const unsigned short* __restrict__ WGi, const unsigned short* __restrict__ WGh,
    const float* __restrict__ mbih, const float* __restrict__ mbhh,
    const unsigned short* __restrict__ WmeT, const float* __restrict__ bme,
    const float* __restrict__ Wout, const float* __restrict__ bout,
    void* __restrict__ out, const unsigned* __restrict__ amtag){
    int b = blockIdx.x, tid = threadIdx.x;
    int wv = tid >> 6, lane = tid & 63;
    int dq = tid & 255, cq = tid >> 8;
    __shared__ unsigned short s_cur[L_*KC];
    __shared__ float s_am[L_], s_neg[L_], s_cd[L_];
    __shared__ float s_wp[4][L_];      // per-wave private softmax weights
    __shared__ __attribute__((aligned(16))) float s_mf[D_];
    __shared__ __attribute__((aligned(16))) float s_act[D_];
    __shared__ __attribute__((aligned(16))) float s_wc[D_];
    __shared__ __attribute__((aligned(16))) float s_ctx[D_];
    __shared__ __attribute__((aligned(16))) float s_mf2[2*D_];
    __shared__ float s_gi[G3D_], s_gh[G3D_];
    __shared__ float s_wma[D_], s_bmt[D_], s_bi[G3D_], s_bh[G3D_];
    __shared__ float s_part[2][256];
    __shared__ float s_red[8];
    __shared__ float s_wsm;
    const uint4* src = (const uint4*)(cur16 + (size_t)b*L_*KC);
    for (int i = tid; i < L_*KC/8; i += 512) ((uint4*)s_cur)[i] = src[i];
    if (tid < L_){
        float am = atom_mask[b*L_ + tid];
        s_am[tid] = am;
        s_neg[tid] = (am == 0.f) ? NEGV : 0.f;
        s_cd[tid] = curdot[b*L_ + tid];
    }
    if (tid < D_){ s_wma[tid] = Wma[tid]; s_bmt[tid] = bmt[tid]; }
    for (int j = tid; j < G3D_; j += 512){
        s_bi[j] = mbih[j];
        s_bh[j] = mbhh[j];
    }
    __syncthreads();
    {   // mol_feature = sum_l am[l]*cur[l,:]
        float a0 = 0.f, a1 = 0.f;
        if (dq < D_)
            for (int l=cq*64; l<cq*64+64; l+=2){
                a0 += bu2f(s_cur[l*KC + dq]) * s_am[l];
                a1 += bu2f(s_cur[(l+1)*KC + dq]) * s_am[l+1];
            }
        s_part[cq][dq] = a0 + a1;
        __syncthreads();
        if (tid < D_){
            float v = s_part[0][tid] + s_part[1][tid];
            s_mf[tid] = v; s_act[tid] = fmaxf(v, 0.f);
        }
        __syncthreads();
    }
    float bma0 = bma[0];
    #pragma unroll 1
    for (int t=0;t<T_;t++){
        if (wv < 4){
            float a = s_act[lane]*s_wma[lane] + s_act[lane+64]*s_wma[lane+64];
            a += s_act[lane+128]*s_wma[lane+128];
            if (lane < 8) a += s_act[lane+192]*s_wma[lane+192];
            #pragma unroll
            for (int o=32;o>0;o>>=1) a += __shfl_xor(a,o);       // s1v
            float sc0 = lreluf(a + s_cd[lane] + bma0) + s_neg[lane];
            float sc1 = lreluf(a + s_cd[lane+64] + bma0) + s_neg[lane+64];
            float m = fmaxf(sc0, sc1);
            #pragma unroll
            for (int o=32;o>0;o>>=1) m = fmaxf(m, __shfl_xor(m,o));
            float e0 = expf(sc0 - m), e1 = expf(sc1 - m);
            float s = e0 + e1;
            #pragma unroll
            for (int o=32;o>0;o>>=1) s += __shfl_xor(s,o);
            float inv = 1.f/s;
            float w0 = e0*inv*s_am[lane], w1 = e1*inv*s_am[lane+64];
            float ws = w0 + w1;
            #pragma unroll
            for (int o=32;o>0;o>>=1) ws += __shfl_xor(ws,o);
            s_wp[wv][lane] = w0; s_wp[wv][lane+64] = w1;
            if (tid == 0) s_wsm = ws;
            if (tid < D_){
                float acc = 0.f;
                #pragma unroll 16
                for (int l=0; l<L_; l++)
                    acc += s_wp[wv][l] * bu2f(s_cur[l*KC + tid]);
                s_wc[tid] = acc;
            }
        } else {
            int h = tid - 256;
            #pragma unroll 1
            for (int rr=0; rr<3; rr++){
                int row = h + rr*256;
                if (row < G3D_)
                    s_gh[row] = dot200(WGh + (size_t)row*D_, s_mf);
                __builtin_amdgcn_sched_barrier(0);
            }
        }
        __syncthreads();   // #1
        if (tid < D_){
            float acc = dot200(WmtT + (size_t)tid*D_, s_wc);
            s_ctx[tid] = eluf(acc + s_wsm * s_bmt[tid]);
        }
        __syncthreads();   // #2
        {
            #pragma unroll 1
            for (int rr=0; rr<2; rr++){
                int row = tid + rr*512;
                if (row < G3D_)
                    s_gi[row] = dot200(WGi + (size_t)row*D_, s_ctx);
                __builtin_amdgcn_sched_barrier(0);
            }
        }
        __syncthreads();   // #3
        if (tid < D_){
            int d = tid;
            float rr = sigmf(s_gi[d] + s_bi[d] + s_gh[d] + s_bh[d]);
            float zz = sigmf(s_gi[D_+d] + s_bi[D_+d] + s_gh[D_+d] + s_bh[D_+d]);
            float nn = tanhf(s_gi[2*D_+d] + s_bi[2*D_+d] + rr*(s_gh[2*D_+d] + s_bh[2*D_+d]));
            float nm = (1.f-zz)*nn + zz*s_mf[d];
            s_mf[d] = nm; s_act[d] = fmaxf(nm, 0.f);
        }
        __syncthreads();   // #4
        __builtin_amdgcn_sched_barrier(0);
    }
    const float dd = (float)(R_ - 2);
    if (tid < 2*D_) s_mf2[tid] = (tid < D_) ? s_mf[tid] : s_mf[tid - D_] + dd;
    __syncthreads();
    float p2 = 0.f;
    if (tid < D_){
        const uint4* wp = (const uint4*)(WmeT + (size_t)tid*400);
        float a0=0.f, a1=0.f;
        #pragma unroll
        for (int kk=0; kk<50; kk++){
            uint4 u = wp[kk];
            f32x4 wA = *(const f32x4*)&s_mf2[8*kk];
            f32x4 wB = *(const f32x4*)&s_mf2[8*kk+4];
            a0 += wA[0]*lo2f(u.x) + wA[1]*hi2f(u.x);
            a1 += wA[2]*lo2f(u.y) + wA[3]*hi2f(u.y);
            a0 += wB[0]*lo2f(u.z) + wB[1]*hi2f(u.z);
            a1 += wB[2]*lo2f(u.w) + wB[3]*hi2f(u.w);
        }
        p2 = (a0 + a1 + bme[tid]) * Wout[tid];
    }
    float o = brSum(p2, s_red);
    if (tid==0){
        o += bout[0];
        if (*amtag == FP32TAG) ((float*)out)[b] = o;
        else ((bf16*)out)[b] = __float2bfloat16(o);
    }
}

extern "C" void kernel_launch(void* const* d_in, const int* in_sizes, int n_in,
                              void* d_out, int out_size, void* d_ws, size_t ws_size,
                              hipStream_t stream) {
    const int* adl = (const int*)d_in[2];
    const int* bdl = (const int*)d_in[3];
    const unsigned* amtag = (const unsigned*)d_in[4];

    static const int srcidx[NSEG] = {4,9,10,12,15,16,17,18,20,23,24,26,27,28};
    static const int segsz[NSEG]  = {16384,1200,3,600,1800,1800,400,1,200,600,600,200,200,1};
    CvtArgs ca;
    int ofs[NSEG+1]; ofs[0] = 0;
    for (int i=0;i<NSEG;i++){ ca.src[i] = d_in[srcidx[i]]; ca.ofs[i] = ofs[i]; ofs[i+1] = ofs[i] + segsz[i]; }
    ca.ofs[NSEG] = ofs[NSEG];   // 23989

    // ws layout. ~55 MB total.
    float* ws   = (float*)d_ws;
    float* conv = ws;                                            // 24000 fl
    unsigned short* XHa   = (unsigned short*)(conv + 24000);     // BL_*KP sh
    unsigned short* B2t   = XHa + (size_t)BL_*KP;                // PREPB_N sh (NP2 layout)
    unsigned short* WatT  = B2t + PREPB_N;                       // PREPW_N sh
    unsigned short* WGi   = WatT + PREPW_N;                      // PREPM_N sh
    unsigned short* WGh   = WGi + PREPM_N;                       // PREPM_N sh
    unsigned short* WmtT  = WGh + PREPM_N;                       // PREPT_N sh
    unsigned short* WmeT  = WmtT + PREPT_N;                      // PREPE_N sh
    unsigned short* Bi16  = WmeT + PREPE_N;                      // BI_N sh
    unsigned short* cur16 = Bi16 + BI_N;                         // BL_*KC sh
    unsigned short* creg  = cur16 + (size_t)BL_*KC;              // region: BL_*NP sh (overlays)
    unsigned short* A16  = creg;                                 // overlay (dead before wnei)
    unsigned short* wnei = creg;                                 // BL_*KC sh overlay
    unsigned short* Q16  = creg + (size_t)BL_*KC;                // B_*MB_*D_ sh overlay (r0 only)
    unsigned short* P16  = Q16 + (size_t)B_*MB_*D_;              // BL_*D_ sh overlay (r0 only)
    unsigned short* XHb  = Q16;                                  // BL_*KP sh overlay (post-r0-attn)
    float* s1     = (float*)(creg + (size_t)BL_*NP);
    float* tb     = s1 + BL_;
    float* wsum   = tb + BL_;
    float* curdot = wsum + BL_;

    const float* c_amask = conv + ofs[0];
    const float* c_Walign= conv + ofs[1];
    const float* c_balign= conv + ofs[2];
    const float* c_batt  = conv + ofs[3];
    const float* c_bih   = conv + ofs[4];
    const float* c_bhh   = conv + ofs[5];
    const float* c_Wma   = conv + ofs[6];
    const float* c_bma   = conv + ofs[7];
    const float* c_bmt   = conv + ofs[8];
    const float* c_mbih  = conv + ofs[9];
    const float* c_mbhh  = conv + ofs[10];
    const float* c_bme   = conv + ofs[11];
    const float* c_Wout  = conv + ofs[12];
    const float* c_bout  = conv + ofs[13];

    PrepArgs A;
    A.cvt = ca;
    A.Wih = d_in[13]; A.Whh = d_in[14]; A.Watt = d_in[11];
    A.mWih = d_in[21]; A.mWhh = d_in[22]; A.Wmt = d_in[19]; A.Wme = d_in[25];
    A.bond = d_in[1]; A.Wnei = d_in[7]; A.atom = d_in[0]; A.Watom = d_in[5];
    A.conv = conv;
    A.B2t = B2t; A.WatT = WatT; A.WGi = WGi; A.WGh = WGh; A.WmtT = WmtT; A.WmeT = WmeT;
    A.XH = XHa; A.A16 = A16; A.Bi16 = Bi16; A.cur16 = cur16;
    A.amtag = amtag;
    A.ew_total = CONV_N + PREPB_N + PREPW_N + PREPG_N + PREPT_N + PREPE_N
               + XHPAD_N + CPAD_N + A_N + BI_N;   // 5663733

    k_prep<<<(A.ew_total + 255)/256, 256, 0, stream>>>(A);
    k_initmm<<<(AROWS/128)*7, 256, 0, stream>>>(A16, Bi16, d_in[6], d_in[8],
                                                XHa, P16, Q16, amtag);

    for (int r=0; r<R_; r++){
        unsigned short* XHr = (r & 1) ? XHb : XHa;   // gemm reads / ctx writes x-half
        unsigned short* XHw = (r & 1) ? XHa : XHb;   // gemm writes h-half (next round's XHr)
        k_attn<<<BL_/4, 256, 0, stream>>>(cur16, XHa, s1, tb, adl, bdl, P16, Q16,
                                          c_Walign, c_balign, r, wnei, wsum);
        k_ctxmfma<<<(BL_/128)*(NC/64), 256, 0, stream>>>(wnei, wsum, WatT, c_batt, r, XHr,
                                                         s1, tb, curdot);
        k_gemm2<<<1024, 256, 0, stream>>>(XHr, XHw, B2t, cur16, c_bih, c_bhh,
                                          c_Walign, c_Wma, s1, tb, curdot, r);
    }

    k_mol<<<B_, 512, 0, stream>>>(cur16, curdot, c_amask, c_Wma, c_bma, WmtT, c_bmt,
                                  WGi, WGh, c_mbih, c_mbhh, WmeT, c_bme, c_Wout, c_bout,
                                  d_out, amtag);
}

// Round 11
// 413.724 us; speedup vs baseline: 1.2423x; 1.2423x over previous
//
#include <hip/hip_runtime.h>
#include <hip/hip_bf16.h>
#include <math.h>
#include <string.h>

#define B_ 128
#define L_ 128
#define N_ 6
#define FA_ 39
#define FB_ 10
#define D_ 200
#define MB_ 256
#define R_ 3
#define T_ 2
#define NEGV -9e8f
#define BL_ (B_*L_)        // 16384
#define G3D_ (3*D_)        // 600
#define FP32TAG 0x3F800000u
#define KP 416             // padded K for gate GEMM
#define NP 896             // padded N for gate GEMM (7*128)
#define KC 224             // padded K for ctx GEMM (7*32)
#define NC 256             // padded N for ctx GEMM

typedef __hip_bfloat16 bf16;
typedef __attribute__((ext_vector_type(8))) short short8;
typedef __attribute__((ext_vector_type(4))) float f32x4;

__device__ __forceinline__ float b2f(const bf16 x){ return __bfloat162float(x); }
__device__ __forceinline__ unsigned short f2b(float v){ bf16 t = __float2bfloat16(v); return *reinterpret_cast<unsigned short*>(&t); }
__device__ __forceinline__ float bu2f(unsigned short u){ unsigned x = ((unsigned)u)<<16; float f; memcpy(&f,&x,4); return f; }
__device__ __forceinline__ float lo2f(unsigned x){ unsigned y = x<<16; float f; memcpy(&f,&y,4); return f; }
__device__ __forceinline__ float hi2f(unsigned x){ unsigned y = x & 0xffff0000u; float f; memcpy(&f,&y,4); return f; }
__device__ __forceinline__ float lreluf(float x){ return x>=0.f ? x : 0.01f*x; }
__device__ __forceinline__ float eluf(float x){ return x>0.f ? x : expm1f(x); }
__device__ __forceinline__ float sigmf(float x){ return 1.f/(1.f+expf(-x)); }

#define NSEG 14
struct CvtArgs { const void* src[NSEG]; int ofs[NSEG+1]; };

#define PREPB_N (R_*NP*KP)     // 1118208
#define PREPW_N (R_*NC*KC)     // 172032
#define PREPM_N (D_*G3D_)      // 120000 (per matrix)
#define PREPG_N (2*PREPM_N)    // 240000 (WGi + WGh flat bf16)
#define PREPT_N 40000          // WmtT [d][k]
#define PREPE_N 80000          // WmeT [d][k0..399]
#define CONV_N 23989
#define XHPAD_N (BL_*16)       // 262144
#define AROWS (BL_ + B_*MB_)   // 49152
#define A_N (AROWS*64)         // 3145728
#define BI_N (448*64)          // 28672

struct PrepArgs {
    CvtArgs cvt;
    const void *Wih, *Whh, *Watt, *mWih, *mWhh, *Wmt, *Wme;
    const void *bond, *Wnei, *atom, *Watom;
    float* conv;
    unsigned short *B2t, *WatT, *WGi, *WGh, *WmtT, *WmeT, *XH, *A16, *Bi16;
    const unsigned* amtag;
    int ew_total;
};

__device__ __forceinline__ float ldd(const void* p, size_t i, bool f32){
    return f32 ? ((const float*)p)[i] : b2f(((const bf16*)p)[i]);
}

// prologue elementwise: small-param convert + all weight repacks + XH pad + A16/Bi16 packing
__global__ void __launch_bounds__(256) k_prep(PrepArgs A){
    bool f32 = (*A.amtag == FP32TAG);
    int i = blockIdx.x*256 + (int)threadIdx.x;
    if (i >= A.ew_total) return;
    if (i < CONV_N){
        int s = 0;
        while (i >= A.cvt.ofs[s+1]) s++;
        A.conv[i] = ldd(A.cvt.src[s], i - A.cvt.ofs[s], f32);
        return;
    }
    int i2 = i - CONV_N;
    if (i2 < PREPB_N){
        int kk = i2 % KP;
        int rest = i2 / KP;
        int n = rest % NP;
        int r = rest / NP;
        float v = 0.f;
        if (kk < 200){
            if (n < 600) v = ldd(A.Wih, ((size_t)(r*G3D_ + n))*D_ + kk, f32);
        } else if (kk < 400){
            int j = -1;
            if (n < 400) j = n;
            else if (n >= 600 && n < 800) j = n - 200;
            if (j >= 0) v = ldd(A.Whh, ((size_t)(r*G3D_ + j))*D_ + (kk-200), f32);
        }
        A.B2t[i2] = f2b(v);
        return;
    }
    int i3 = i2 - PREPB_N;
    if (i3 < PREPW_N){
        int kk = i3 % KC;
        int rest = i3 / KC;
        int n = rest % NC;
        int r = rest / NC;
        float v = 0.f;
        if (kk < 200 && n < 200) v = ldd(A.Watt, ((size_t)r*D_ + kk)*D_ + n, f32);
        A.WatT[i3] = f2b(v);
        return;
    }
    int i4 = i3 - PREPW_N;
    if (i4 < PREPG_N){
        // WGi = mWih rows (row-per-output already), WGh = mWhh rows; flat bf16 convert
        int half = i4 / PREPM_N;
        int s = i4 - half*PREPM_N;
        (half ? A.WGh : A.WGi)[s] = f2b(ldd(half ? A.mWhh : A.mWih, s, f32));
        return;
    }
    int i5 = i4 - PREPG_N;
    if (i5 < PREPT_N){
        // WmtT[d*200+k] = Wmt[k*200+d]; source-ordered reads
        int k = i5 / 200, d = i5 % 200;
        A.WmtT[(size_t)d*200 + k] = f2b(ldd(A.Wmt, i5, f32));
        return;
    }
    int i6 = i5 - PREPT_N;
    if (i6 < PREPE_N){
        // WmeT[d*400+k] = Wme[k*200+d], k<400; source-ordered reads
        int k = i6 / 200, d = i6 % 200;
        A.WmeT[(size_t)d*400 + k] = f2b(ldd(A.Wme, i6, f32));
        return;
    }
    int i7 = i6 - PREPE_N;
    if (i7 < XHPAD_N){
        int al = i7 >> 4, j = i7 & 15;
        A.XH[(size_t)al*KP + 400 + j] = 0;
        return;
    }
    int i8 = i7 - XHPAD_N;
    if (i8 < A_N){
        int row = i8 >> 6, k = i8 & 63;
        float v = 0.f;
        if (row < BL_){
            if (k < FA_) v = ldd(A.atom, (size_t)row*FA_ + k, f32);
        } else {
            int rb = row - BL_;
            if (k >= FA_ && k < FA_+FB_) v = ldd(A.bond, (size_t)rb*FB_ + (k-FA_), f32);
        }
        A.A16[i8] = f2b(v);
        return;
    }
    int i9 = i8 - A_N;
    if (i9 < BI_N){
        int n = i9 >> 6, k = i9 & 63;
        float v = 0.f;
        if (n < 200){
            if (k < FA_) v = ldd(A.Watom, (size_t)k*D_ + n, f32);
        } else if (n < 400){
            if (k < FA_+FB_) v = ldd(A.Wnei, (size_t)k*D_ + (n-200), f32);
        }
        A.Bi16[i9] = f2b(v);
    }
}

// MFMA init GEMM: C[49152,448] = A16 @ Bi16^T. Atom rows -> XH h-half (lrelu+b_atom) and
// P16 (+b_nei); bond rows -> Q16. 128x64 tile, K=64 (2 steps).
__global__ void __launch_bounds__(256) k_initmm(const unsigned short* __restrict__ A16,
        const unsigned short* __restrict__ Bi16,
        const void* __restrict__ batom, const void* __restrict__ bnei,
        unsigned short* __restrict__ XH, unsigned short* __restrict__ P16,
        unsigned short* __restrict__ Q16, const unsigned* __restrict__ amtag){
    __shared__ unsigned short As[128][40];
    __shared__ unsigned short Bs[64][40];
    bool f32 = (*amtag == FP32TAG);
    int tid = threadIdx.x;
    int mt = (int)blockIdx.x / 7, nt = (int)blockIdx.x % 7;
    int m0 = mt*128, n0 = nt*64;
    if (m0 >= BL_ && n0 + 64 <= 200) return;   // bond rows x atom-feature cols: all dead
    int lane = tid & 63, wv = tid >> 6;
    int quad = lane >> 4, lm = lane & 15;
    f32x4 acc[2][4];
    #pragma unroll
    for (int a=0;a<2;a++)
        #pragma unroll
        for (int b=0;b<4;b++) acc[a][b] = (f32x4){0.f,0.f,0.f,0.f};
    for (int ks = 0; ks < 2; ks++){
        int r0_ = tid >> 2, c0 = (tid & 3) * 8;
        int r1_ = (tid + 256) >> 2, c1 = ((tid + 256) & 3) * 8;
        uint4 a0 = *(const uint4*)&A16[(size_t)(m0 + r0_)*64 + ks*32 + c0];
        uint4 a1 = *(const uint4*)&A16[(size_t)(m0 + r1_)*64 + ks*32 + c1];
        uint4 b0 = *(const uint4*)&Bi16[(size_t)(n0 + (tid >> 2))*64 + ks*32 + (tid & 3)*8];
        __syncthreads();
        *(uint4*)&As[r0_][c0] = a0;
        *(uint4*)&As[r1_][c1] = a1;
        *(uint4*)&Bs[tid >> 2][(tid & 3)*8] = b0;
        __syncthreads();
        short8 av0 = *(const short8*)&As[wv*32 + lm][quad*8];
        short8 av1 = *(const short8*)&As[wv*32 + 16 + lm][quad*8];
        #pragma unroll
        for (int ns=0; ns<4; ns++){
            short8 bv = *(const short8*)&Bs[ns*16 + lm][quad*8];
            acc[0][ns] = __builtin_amdgcn_mfma_f32_16x16x32_bf16(av0, bv, acc[0][ns], 0,0,0);
            acc[1][ns] = __builtin_amdgcn_mfma_f32_16x16x32_bf16(av1, bv, acc[1][ns], 0,0,0);
        }
    }
    #pragma unroll
    for (int ms=0; ms<2; ms++)
      #pragma unroll
      for (int ns=0; ns<4; ns++){
        int n = n0 + ns*16 + lm;
        #pragma unroll
        for (int i=0;i<4;i++){
            int row = m0 + wv*32 + ms*16 + quad*4 + i;
            float v = acc[ms][ns][i];
            if (row < BL_){
                if (n < 200){
                    XH[(size_t)row*KP + 200 + n] = f2b(lreluf(v + ldd(batom, n, f32)));
                } else if (n < 400){
                    P16[(size_t)row*D_ + (n-200)] = f2b(v + ldd(bnei, n-200, f32));
                }
            } else if (n >= 200 && n < 400){
                Q16[(size_t)(row-BL_)*D_ + (n-200)] = f2b(v);
            }
        }
      }
}

// attention (all rounds): softmax + weighted neighbor sum -> bf16 wnei (stride KC, zero pad).
// XCD-locality swizzle: mol = bid&127. r0: compile-time-unrolled n (no div, no
// runtime-indexed idxn), fused Wab dot into the s_nei fill, interleaved shfl reductions.
__global__ void __launch_bounds__(256) k_attn(
        const unsigned short* __restrict__ cur16, const unsigned short* __restrict__ XH,
        const float* __restrict__ s1, const float* __restrict__ tb,
        const int* __restrict__ adl, const int* __restrict__ bdl,
        const unsigned short* __restrict__ P16, const unsigned short* __restrict__ Q16,
        const float* __restrict__ W_align, const float* __restrict__ b_align, int r,
        unsigned short* __restrict__ wnei, float* __restrict__ wsum){
    int bid = blockIdx.x;
    int mol = bid & (B_-1), chunk = bid >> 7;
    int wv = threadIdx.x >> 6, lane = threadIdx.x & 63;
    int al = mol*L_ + chunk*4 + wv;
    __shared__ float s_nei[4][N_][D_];

    int idxn[N_]; bool pad[N_];
    #pragma unroll
    for (int n=0;n<N_;n++){ idxn[n] = adl[al*N_ + n]; pad[n] = (idxn[n] == L_-1); }

    float s2[N_];
    float s1v;
    if (r == 0){
        const float* Wab = W_align + D_;
        float acc[N_+1];
        #pragma unroll
        for (int n=0;n<N_+1;n++) acc[n] = 0.f;
        #pragma unroll
        for (int n=0;n<N_;n++){
            int bd = bdl[al*N_ + n];
            const unsigned short* Prow = P16 + ((size_t)mol*L_ + idxn[n])*D_;
            const unsigned short* Qrow = Q16 + ((size_t)mol*MB_ + bd)*D_;
            for (int d=lane; d<D_; d+=64){
                float v = lreluf(bu2f(Prow[d]) + bu2f(Qrow[d]));
                s_nei[wv][n][d] = v;
                acc[n] += v * Wab[d];
            }
        }
        for (int d=lane; d<D_; d+=64)
            acc[N_] += bu2f(XH[(size_t)al*KP + 200 + d]) * W_align[d];
        #pragma unroll
        for (int o=32;o>0;o>>=1)
            #pragma unroll
            for (int n=0;n<N_+1;n++) acc[n] += __shfl_xor(acc[n],o);
        #pragma unroll
        for (int n=0;n<N_;n++) s2[n] = acc[n];
        s1v = acc[N_];
    } else {
        float tmp = 0.f;
        if (lane < N_) tmp = tb[mol*L_ + idxn[lane]];
        #pragma unroll
        for (int n=0;n<N_;n++) s2[n] = __shfl(tmp, n);
        s1v = s1[al];
    }

    float bav = b_align[r];
    float a[N_]; float mx = -1e30f;
    #pragma unroll
    for (int n=0;n<N_;n++){
        float v = lreluf(s1v + s2[n] + bav);
        if (pad[n]) v += NEGV;
        a[n] = v; mx = fmaxf(mx, v);
    }
    float w[N_]; float se = 0.f;
    #pragma unroll
    for (int n=0;n<N_;n++){ float e = expf(a[n]-mx); w[n]=e; se += e; }
    float inv = 1.f/se; float wsv = 0.f;
    #pragma unroll
    for (int n=0;n<N_;n++){ w[n] = pad[n] ? 0.f : w[n]*inv; wsv += w[n]; }

    if (r == 0){
        for (int d=lane; d<D_; d+=64){
            float acc = 0.f;
            #pragma unroll
            for (int n=0;n<N_;n++) acc += w[n] * s_nei[wv][n][d];
            wnei[(size_t)al*KC + d] = f2b(acc);
        }
    } else {
        for (int d=lane; d<D_; d+=64){
            float acc = 0.f;
            #pragma unroll
            for (int n=0;n<N_;n++) acc += w[n] * bu2f(cur16[((size_t)mol*L_ + idxn[n])*KC + d]);
            wnei[(size_t)al*KC + d] = f2b(acc);
        }
    }
    if (lane < 24) wnei[(size_t)al*KC + 200 + lane] = 0;
    if (lane==0) wsum[al] = wsv;
}

// MFMA ctx GEMM: elu(wnei[16384,KC] @ WatT[r]^T + wsum*bias) -> XH x-half. 128x64 tile.
__global__ void __launch_bounds__(256) k_ctxmfma(const unsigned short* __restrict__ Wn,
        const float* __restrict__ wsum, const unsigned short* __restrict__ WatT,
        const float* __restrict__ bias, int r, unsigned short* __restrict__ XH){
    __shared__ unsigned short As[128][40];
    __shared__ unsigned short Bs[64][40];
    int tid = threadIdx.x;
    int m0 = ((int)blockIdx.x & 127) * 128;
    int n0 = ((int)blockIdx.x >> 7) * 64;
    const unsigned short* Bt = WatT + (size_t)r*NC*KC;
    int lane = tid & 63, wv = tid >> 6;
    int quad = lane >> 4, lm = lane & 15;
    f32x4 acc[2][4];
    #pragma unroll
    for (int a=0;a<2;a++)
        #pragma unroll
        for (int b=0;b<4;b++) acc[a][b] = (f32x4){0.f,0.f,0.f,0.f};
    for (int ks = 0; ks < 7; ks++){
        int r0_ = tid >> 2, c0 = (tid & 3) * 8;
        int r1_ = (tid + 256) >> 2, c1 = ((tid + 256) & 3) * 8;
        uint4 a0 = *(const uint4*)&Wn[(size_t)(m0 + r0_)*KC + ks*32 + c0];
        uint4 a1 = *(const uint4*)&Wn[(size_t)(m0 + r1_)*KC + ks*32 + c1];
        uint4 b0 = *(const uint4*)&Bt[(size_t)(n0 + (tid >> 2))*KC + ks*32 + (tid & 3)*8];
        __syncthreads();
        *(uint4*)&As[r0_][c0] = a0;
        *(uint4*)&As[r1_][c1] = a1;
        *(uint4*)&Bs[tid >> 2][(tid & 3)*8] = b0;
        __syncthreads();
        short8 av0 = *(const short8*)&As[wv*32 + lm][quad*8];
        short8 av1 = *(const short8*)&As[wv*32 + 16 + lm][quad*8];
        #pragma unroll
        for (int ns=0; ns<4; ns++){
            short8 bv = *(const short8*)&Bs[ns*16 + lm][quad*8];
            acc[0][ns] = __builtin_amdgcn_mfma_f32_16x16x32_bf16(av0, bv, acc[0][ns], 0,0,0);
            acc[1][ns] = __builtin_amdgcn_mfma_f32_16x16x32_bf16(av1, bv, acc[1][ns], 0,0,0);
        }
    }
    #pragma unroll
    for (int ms=0; ms<2; ms++)
      #pragma unroll
      for (int ns=0; ns<4; ns++){
        int n = n0 + ns*16 + lm;
        if (n < 200){
            float bv = bias[r*D_ + n];
            #pragma unroll
            for (int i=0;i<4;i++){
                int row = m0 + wv*32 + ms*16 + quad*4 + i;
                float v = acc[ms][ns][i] + wsum[row]*bv;
                XH[(size_t)row*KP + n] = f2b(eluf(v));
            }
        }
      }
}

// MFMA gate GEMM: C[16384,NP] = XH @ B2t[r]^T. 128x128 tile.
__global__ void __launch_bounds__(256) k_gemm(const unsigned short* __restrict__ XH,
        const unsigned short* __restrict__ B2t, unsigned short* __restrict__ C, int r){
    __shared__ unsigned short As[128][40];
    __shared__ unsigned short Bs[128][40];
    int tid = threadIdx.x;
    int m0 = ((int)blockIdx.x & 127) * 128;
    int n0 = ((int)blockIdx.x >> 7) * 128;
    const unsigned short* Bt = B2t + (size_t)r*NP*KP;
    int lane = tid & 63, wv = tid >> 6;
    int quad = lane >> 4, lm = lane & 15;
    f32x4 acc[2][8];
    #pragma unroll
    for (int a=0;a<2;a++)
        #pragma unroll
        for (int b=0;b<8;b++) acc[a][b] = (f32x4){0.f,0.f,0.f,0.f};
    for (int ks = 0; ks < 13; ks++){
        int r0_ = tid >> 2, c0 = (tid & 3) * 8;
        int r1_ = (tid + 256) >> 2, c1 = ((tid + 256) & 3) * 8;
        uint4 a0 = *(const uint4*)&XH[(size_t)(m0 + r0_)*KP + ks*32 + c0];
        uint4 a1 = *(const uint4*)&XH[(size_t)(m0 + r1_)*KP + ks*32 + c1];
        uint4 b0 = *(const uint4*)&Bt[(size_t)(n0 + r0_)*KP + ks*32 + c0];
        uint4 b1 = *(const uint4*)&Bt[(size_t)(n0 + r1_)*KP + ks*32 + c1];
        __syncthreads();
        *(uint4*)&As[r0_][c0] = a0;
        *(uint4*)&As[r1_][c1] = a1;
        *(uint4*)&Bs[r0_][c0] = b0;
        *(uint4*)&Bs[r1_][c1] = b1;
        __syncthreads();
        short8 av0 = *(const short8*)&As[wv*32 + lm][quad*8];
        short8 av1 = *(const short8*)&As[wv*32 + 16 + lm][quad*8];
        #pragma unroll
        for (int ns=0; ns<8; ns++){
            short8 bv = *(const short8*)&Bs[ns*16 + lm][quad*8];
            acc[0][ns] = __builtin_amdgcn_mfma_f32_16x16x32_bf16(av0, bv, acc[0][ns], 0,0,0);
            acc[1][ns] = __builtin_amdgcn_mfma_f32_16x16x32_bf16(av1, bv, acc[1][ns], 0,0,0);
        }
    }
    #pragma unroll
    for (int ms=0; ms<2; ms++)
      #pragma unroll
      for (int ns=0; ns<8; ns++)
        #pragma unroll
        for (int i=0;i<4;i++){
            int row = m0 + wv*32 + ms*16 + quad*4 + i;
            C[(size_t)row*NP + n0 + ns*16 + lm] = f2b(acc[ms][ns][i]);
        }
}

// GRU combine, wave-per-atom; GRU state lives in XH h-half (bf16). Writes cur16;
// fuses next-round s1/tb dots (r<2) or curdot (r==2).
__global__ void __launch_bounds__(256) k_gru2(const unsigned short* __restrict__ C,
        unsigned short* __restrict__ XH, unsigned short* __restrict__ cur16,
        const float* __restrict__ bih, const float* __restrict__ bhh,
        const float* __restrict__ W_align, const float* __restrict__ Wma, int r,
        float* __restrict__ s1, float* __restrict__ tb, float* __restrict__ curdot){
    int wv = threadIdx.x >> 6, lane = threadIdx.x & 63;
    int al = blockIdx.x*4 + wv;
    size_t base = (size_t)al*NP;
    const float* bi = bih + r*G3D_;
    const float* bh = bhh + r*G3D_;
    const float* Wa = W_align + (r+1)*2*D_;   // dereferenced only when r<2
    bool last = (r == R_-1);
    float a1 = 0.f, a2 = 0.f;
    for (int j = lane; j < D_; j += 64){
        float rsum = bu2f(C[base + j]);
        float zsum = bu2f(C[base + 200 + j]);
        float gin  = bu2f(C[base + 400 + j]);
        float ghn  = bu2f(C[base + 600 + j]);
        float rr = sigmf(rsum + bi[j] + bh[j]);
        float zz = sigmf(zsum + bi[D_+j] + bh[D_+j]);
        float nn = tanhf(gin + bi[2*D_+j] + rr*(ghn + bh[2*D_+j]));
        size_t hx = (size_t)al*KP + 200 + j;
        float hv = bu2f(XH[hx]);
        float hn = (1.f-zz)*nn + zz*hv;
        XH[hx] = f2b(hn);
        float cv = fmaxf(hn, 0.f);
        cur16[(size_t)al*KC + j] = f2b(cv);
        if (last){
            a1 += cv * Wma[D_+j];
        } else {
            a1 += cv * Wa[j];
            a2 += cv * Wa[D_+j];
        }
    }
    if (lane < 24) cur16[(size_t)al*KC + 200 + lane] = 0;
    for (int o=32;o>0;o>>=1){ a1 += __shfl_xor(a1,o); a2 += __shfl_xor(a2,o); }
    if (lane==0){
        if (last) curdot[al] = a1;
        else { s1[al] = a1; tb[al] = a2; }
    }
}

__device__ __forceinline__ float brSum(float v, float* s_red){
    for (int o=32;o>0;o>>=1) v += __shfl_xor(v,o);
    int lane = threadIdx.x & 63, wid = threadIdx.x >> 6;
    __syncthreads();
    if (lane==0) s_red[wid] = v;
    __syncthreads();
    float r = 0.f;
    int nw = blockDim.x >> 6;
    for (int i=0;i<nw;i++) r += s_red[i];
    return r;
}

// 200-elem dot of a bf16 row (25x uint4) with an LDS f32 vector (16B-aligned)
__device__ __forceinline__ float dot200(const unsigned short* __restrict__ wrow,
                                        const float* __restrict__ v){
    const uint4* wp = (const uint4*)wrow;
    float a0=0.f, a1=0.f;
    #pragma unroll
    for (int kk=0; kk<25; kk++){
        uint4 u = wp[kk];
        f32x4 A = *(const f32x4*)&v[8*kk];
        f32x4 Bv = *(const f32x4*)&v[8*kk+4];
        a0 += A[0]*lo2f(u.x) + A[1]*hi2f(u.x);
        a1 += A[2]*lo2f(u.y) + A[3]*hi2f(u.y);
        a0 += Bv[0]*lo2f(u.z) + Bv[1]*hi2f(u.z);
        a1 += Bv[2]*lo2f(u.w) + Bv[3]*hi2f(u.w);
    }
    return a0 + a1;
}

// molecule phase, 512 threads (8 waves), phase-minimized (4 barriers/t-iter).
// Waves 0-3: full softmax redundantly in-register + wc; waves 4-7: gh GEMV concurrently.
// __launch_bounds__(512,1): only 128 blocks exist (1/CU), so do NOT let the compiler
// cap VGPR at 128 for a useless 2-blocks/CU target (R6: cap -> 1MB spill -> 73us).
// sched_barrier(0) after each GEMV row pins the live set (no cross-row load hoisting).
__global__ void __launch_bounds__(512, 1) k_mol(const unsigned short* __restrict__ cur16,
    const float* __restrict__ curdot, const float* __restrict__ atom_mask,
    const float* __restrict__ Wma, const float* __restrict__ bma,
    const unsigned short* __restrict__ WmtT, const float* __restrict__ bmt,
    const unsigned short* __restrict__ WGi, const unsigned short* __restrict__ WGh,
    const float* __restrict__ mbih, const float* __restrict__ mbhh,
    const unsigned short* __restrict__ WmeT, const float* __restrict__ bme,
    const float* __restrict__ Wout, const float* __restrict__ bout,
    void* __restrict__ out, const unsigned* __restrict__ amtag){
    int b = blockIdx.x, tid = threadIdx.x;
    int wv = tid >> 6, lane = tid & 63;
    int dq = tid & 255, cq = tid >> 8;
    __shared__ unsigned short s_cur[L_*KC];
    __shared__ float s_am[L_], s_neg[L_], s_cd[L_];
    __shared__ float s_wp[4][L_];      // per-wave private softmax weights
    __shared__ __attribute__((aligned(16))) float s_mf[D_];
    __shared__ __attribute__((aligned(16))) float s_act[D_];
    __shared__ __attribute__((aligned(16))) float s_wc[D_];
    __shared__ __attribute__((aligned(16))) float s_ctx[D_];
    __shared__ __attribute__((aligned(16))) float s_mf2[2*D_];
    __shared__ float s_gi[G3D_], s_gh[G3D_];
    __shared__ float s_wma[D_], s_bmt[D_], s_bi[G3D_], s_bh[G3D_];
    __shared__ float s_part[2][256];
    __shared__ float s_red[8];
    __shared__ float s_wsm;
    const uint4* src = (const uint4*)(cur16 + (size_t)b*L_*KC);
    for (int i = tid; i < L_*KC/8; i += 512) ((uint4*)s_cur)[i] = src[i];
    if (tid < L_){
        float am = atom_mask[b*L_ + tid];
        s_am[tid] = am;
        s_neg[tid] = (am == 0.f) ? NEGV : 0.f;
        s_cd[tid] = curdot[b*L_ + tid];
    }
    if (tid < D_){ s_wma[tid] = Wma[tid]; s_bmt[tid] = bmt[tid]; }
    for (int j = tid; j < G3D_; j += 512){
        s_bi[j] = mbih[j];
        s_bh[j] = mbhh[j];
    }
    __syncthreads();
    {   // mol_feature = sum_l am[l]*cur[l,:]
        float a0 = 0.f, a1 = 0.f;
        if (dq < D_)
            for (int l=cq*64; l<cq*64+64; l+=2){
                a0 += bu2f(s_cur[l*KC + dq]) * s_am[l];
                a1 += bu2f(s_cur[(l+1)*KC + dq]) * s_am[l+1];
            }
        s_part[cq][dq] = a0 + a1;
        __syncthreads();
        if (tid < D_){
            float v = s_part[0][tid] + s_part[1][tid];
            s_mf[tid] = v; s_act[tid] = fmaxf(v, 0.f);
        }
        __syncthreads();
    }
    float bma0 = bma[0];
    #pragma unroll 1
    for (int t=0;t<T_;t++){
        if (wv < 4){
            // ---- redundant in-wave softmax (no block reductions) ----
            float a = s_act[lane]*s_wma[lane] + s_act[lane+64]*s_wma[lane+64];
            a += s_act[lane+128]*s_wma[lane+128];
            if (lane < 8) a += s_act[lane+192]*s_wma[lane+192];
            #pragma unroll
            for (int o=32;o>0;o>>=1) a += __shfl_xor(a,o);       // s1v
            float sc0 = lreluf(a + s_cd[lane] + bma0) + s_neg[lane];
            float sc1 = lreluf(a + s_cd[lane+64] + bma0) + s_neg[lane+64];
            float m = fmaxf(sc0, sc1);
            #pragma unroll
            for (int o=32;o>0;o>>=1) m = fmaxf(m, __shfl_xor(m,o));
            float e0 = expf(sc0 - m), e1 = expf(sc1 - m);
            float s = e0 + e1;
            #pragma unroll
            for (int o=32;o>0;o>>=1) s += __shfl_xor(s,o);
            float inv = 1.f/s;
            float w0 = e0*inv*s_am[lane], w1 = e1*inv*s_am[lane+64];
            float ws = w0 + w1;
            #pragma unroll
            for (int o=32;o>0;o>>=1) ws += __shfl_xor(ws,o);
            s_wp[wv][lane] = w0; s_wp[wv][lane+64] = w1;
            if (tid == 0) s_wsm = ws;
            // ---- wc[d] = sum_l w[l]*cur[l][d]  (d = tid, own wave's w copy) ----
            if (tid < D_){
                float acc = 0.f;
                #pragma unroll 16
                for (int l=0; l<L_; l++)
                    acc += s_wp[wv][l] * bu2f(s_cur[l*KC + tid]);
                s_wc[tid] = acc;
            }
        } else {
            // ---- gh GEMV (depends only on s_mf): 600 rows over 256 threads ----
            int h = tid - 256;
            #pragma unroll 1
            for (int rr=0; rr<3; rr++){
                int row = h + rr*256;
                if (row < G3D_)
                    s_gh[row] = dot200(WGh + (size_t)row*D_, s_mf);
                __builtin_amdgcn_sched_barrier(0);   // pin live set per row
            }
        }
        __syncthreads();   // #1: s_wc, s_gh, s_wsm ready
        if (tid < D_){
            float acc = dot200(WmtT + (size_t)tid*D_, s_wc);
            s_ctx[tid] = eluf(acc + s_wsm * s_bmt[tid]);
        }
        __syncthreads();   // #2: s_ctx ready
        {
            #pragma unroll 1
            for (int rr=0; rr<2; rr++){
                int row = tid + rr*512;
                if (row < G3D_)
                    s_gi[row] = dot200(WGi + (size_t)row*D_, s_ctx);
                __builtin_amdgcn_sched_barrier(0);   // pin live set per row
            }
        }
        __syncthreads();   // #3: s_gi ready
        if (tid < D_){
            int d = tid;
            float rr = sigmf(s_gi[d] + s_bi[d] + s_gh[d] + s_bh[d]);
            float zz = sigmf(s_gi[D_+d] + s_bi[D_+d] + s_gh[D_+d] + s_bh[D_+d]);
            float nn = tanhf(s_gi[2*D_+d] + s_bi[2*D_+d] + rr*(s_gh[2*D_+d] + s_bh[2*D_+d]));
            float nm = (1.f-zz)*nn + zz*s_mf[d];
            s_mf[d] = nm; s_act[d] = fmaxf(nm, 0.f);
        }
        __syncthreads();   // #4: s_mf/s_act for next t (or epilogue)
        __builtin_amdgcn_sched_barrier(0);           // no cross-t pipelining
    }
    const float dd = (float)(R_ - 2);
    if (tid < 2*D_) s_mf2[tid] = (tid < D_) ? s_mf[tid] : s_mf[tid - D_] + dd;
    __syncthreads();
    float p2 = 0.f;
    if (tid < D_){
        const uint4* wp = (const uint4*)(WmeT + (size_t)tid*400);
        float a0=0.f, a1=0.f;
        #pragma unroll
        for (int kk=0; kk<50; kk++){
            uint4 u = wp[kk];
            f32x4 wA = *(const f32x4*)&s_mf2[8*kk];
            f32x4 wB = *(const f32x4*)&s_mf2[8*kk+4];
            a0 += wA[0]*lo2f(u.x) + wA[1]*hi2f(u.x);
            a1 += wA[2]*lo2f(u.y) + wA[3]*hi2f(u.y);
            a0 += wB[0]*lo2f(u.z) + wB[1]*hi2f(u.z);
            a1 += wB[2]*lo2f(u.w) + wB[3]*hi2f(u.w);
        }
        p2 = (a0 + a1 + bme[tid]) * Wout[tid];
    }
    float o = brSum(p2, s_red);
    if (tid==0){
        o += bout[0];
        if (*amtag == FP32TAG) ((float*)out)[b] = o;
        else ((bf16*)out)[b] = __float2bfloat16(o);
    }
}

extern "C" void kernel_launch(void* const* d_in, const int* in_sizes, int n_in,
                              void* d_out, int out_size, void* d_ws, size_t ws_size,
                              hipStream_t stream) {
    const int* adl = (const int*)d_in[2];
    const int* bdl = (const int*)d_in[3];
    const unsigned* amtag = (const unsigned*)d_in[4];

    static const int srcidx[NSEG] = {4,9,10,12,15,16,17,18,20,23,24,26,27,28};
    static const int segsz[NSEG]  = {16384,1200,3,600,1800,1800,400,1,200,600,600,200,200,1};
    CvtArgs ca;
    int ofs[NSEG+1]; ofs[0] = 0;
    for (int i=0;i<NSEG;i++){ ca.src[i] = d_in[srcidx[i]]; ca.ofs[i] = ofs[i]; ofs[i+1] = ofs[i] + segsz[i]; }
    ca.ofs[NSEG] = ofs[NSEG];   // 23989

    // ws layout. ~54 MB total.
    float* ws   = (float*)d_ws;
    float* conv = ws;                                            // 24000 fl
    unsigned short* XH    = (unsigned short*)(conv + 24000);     // BL_*KP sh
    unsigned short* B2t   = XH + (size_t)BL_*KP;                 // PREPB_N sh
    unsigned short* WatT  = B2t + PREPB_N;                       // PREPW_N sh
    unsigned short* WGi   = WatT + PREPW_N;                      // PREPM_N sh
    unsigned short* WGh   = WGi + PREPM_N;                       // PREPM_N sh
    unsigned short* WmtT  = WGh + PREPM_N;                       // PREPT_N sh
    unsigned short* WmeT  = WmtT + PREPT_N;                      // PREPE_N sh
    unsigned short* Bi16  = WmeT + PREPE_N;                      // BI_N sh
    unsigned short* cur16 = Bi16 + BI_N;                         // BL_*KC sh
    unsigned short* creg  = cur16 + (size_t)BL_*KC;              // C region: BL_*NP sh
    unsigned short* C = creg;
    unsigned short* A16  = creg;                                 // overlay (dead before wnei)
    unsigned short* wnei = creg;                                 // BL_*KC sh overlay
    unsigned short* Q16  = creg + (size_t)BL_*KC;                // B_*MB_*D_ sh overlay
    unsigned short* P16  = Q16 + (size_t)B_*MB_*D_;              // BL_*D_ sh overlay
    float* s1     = (float*)(creg + (size_t)BL_*NP);
    float* tb     = s1 + BL_;
    float* wsum   = tb + BL_;
    float* curdot = wsum + BL_;

    const float* c_amask = conv + ofs[0];
    const float* c_Walign= conv + ofs[1];
    const float* c_balign= conv + ofs[2];
    const float* c_batt  = conv + ofs[3];
    const float* c_bih   = conv + ofs[4];
    const float* c_bhh   = conv + ofs[5];
    const float* c_Wma   = conv + ofs[6];
    const float* c_bma   = conv + ofs[7];
    const float* c_bmt   = conv + ofs[8];
    const float* c_mbih  = conv + ofs[9];
    const float* c_mbhh  = conv + ofs[10];
    const float* c_bme   = conv + ofs[11];
    const float* c_Wout  = conv + ofs[12];
    const float* c_bout  = conv + ofs[13];

    PrepArgs A;
    A.cvt = ca;
    A.Wih = d_in[13]; A.Whh = d_in[14]; A.Watt = d_in[11];
    A.mWih = d_in[21]; A.mWhh = d_in[22]; A.Wmt = d_in[19]; A.Wme = d_in[25];
    A.bond = d_in[1]; A.Wnei = d_in[7]; A.atom = d_in[0]; A.Watom = d_in[5];
    A.conv = conv;
    A.B2t = B2t; A.WatT = WatT; A.WGi = WGi; A.WGh = WGh; A.WmtT = WmtT; A.WmeT = WmeT;
    A.XH = XH; A.A16 = A16; A.Bi16 = Bi16;
    A.amtag = amtag;
    A.ew_total = CONV_N + PREPB_N + PREPW_N + PREPG_N + PREPT_N + PREPE_N
               + XHPAD_N + A_N + BI_N;   // 5110773

    k_prep<<<(A.ew_total + 255)/256, 256, 0, stream>>>(A);
    k_initmm<<<(AROWS/128)*7, 256, 0, stream>>>(A16, Bi16, d_in[6], d_in[8],
                                                XH, P16, Q16, amtag);

    for (int r=0; r<R_; r++){
        k_attn<<<BL_/4, 256, 0, stream>>>(cur16, XH, s1, tb, adl, bdl, P16, Q16,
                                          c_Walign, c_balign, r, wnei, wsum);
        k_ctxmfma<<<(BL_/128)*(NC/64), 256, 0, stream>>>(wnei, wsum, WatT, c_batt, r, XH);
        k_gemm<<<(BL_/128)*(NP/128), 256, 0, stream>>>(XH, B2t, C, r);
        k_gru2<<<BL_/4, 256, 0, stream>>>(C, XH, cur16, c_bih, c_bhh,
                                          c_Walign, c_Wma, r, s1, tb, curdot);
    }

    k_mol<<<B_, 512, 0, stream>>>(cur16, curdot, c_amask, c_Wma, c_bma, WmtT, c_bmt,
                                  WGi, WGh, c_mbih, c_mbhh, WmeT, c_bme, c_Wout, c_bout,
                                  d_out, amtag);
}

// Round 12
// 405.111 us; speedup vs baseline: 1.2687x; 1.0213x over previous
//
#include <hip/hip_runtime.h>
#include <hip/hip_bf16.h>
#include <math.h>
#include <string.h>

#define B_ 128
#define L_ 128
#define N_ 6
#define FA_ 39
#define FB_ 10
#define D_ 200
#define MB_ 256
#define R_ 3
#define T_ 2
#define NEGV -9e8f
#define BL_ (B_*L_)        // 16384
#define G3D_ (3*D_)        // 600
#define FP32TAG 0x3F800000u
#define KP 416             // padded K for gate GEMM
#define NP 896             // padded N for gate GEMM (C stride; cols 800+ dead)
#define NT2 13             // k_gemm n-tiles of 64 (13*64=832 >= 800 live cols)
#define KC 224             // padded K for ctx GEMM (7*32)
#define NC 256             // padded N for ctx GEMM

typedef __hip_bfloat16 bf16;
typedef __attribute__((ext_vector_type(8))) short short8;
typedef __attribute__((ext_vector_type(4))) float f32x4;

__device__ __forceinline__ float b2f(const bf16 x){ return __bfloat162float(x); }
__device__ __forceinline__ unsigned short f2b(float v){ bf16 t = __float2bfloat16(v); return *reinterpret_cast<unsigned short*>(&t); }
__device__ __forceinline__ float bu2f(unsigned short u){ unsigned x = ((unsigned)u)<<16; float f; memcpy(&f,&x,4); return f; }
__device__ __forceinline__ float lo2f(unsigned x){ unsigned y = x<<16; float f; memcpy(&f,&y,4); return f; }
__device__ __forceinline__ float hi2f(unsigned x){ unsigned y = x & 0xffff0000u; float f; memcpy(&f,&y,4); return f; }
__device__ __forceinline__ float lreluf(float x){ return x>=0.f ? x : 0.01f*x; }
__device__ __forceinline__ float eluf(float x){ return x>0.f ? x : expm1f(x); }
__device__ __forceinline__ float sigmf(float x){ return 1.f/(1.f+expf(-x)); }

#define NSEG 14
struct CvtArgs { const void* src[NSEG]; int ofs[NSEG+1]; };

#define PREPB_N (R_*NP*KP)     // 1118208
#define PREPW_N (R_*NC*KC)     // 172032
#define PREPM_N (D_*G3D_)      // 120000 (per matrix)
#define PREPG_N (2*PREPM_N)    // 240000 (WGi + WGh flat bf16)
#define PREPT_N 40000          // WmtT [d][k]
#define PREPE_N 80000          // WmeT [d][k0..399]
#define CONV_N 23989
#define XHPAD_N (BL_*16)       // 262144
#define AROWS (BL_ + B_*MB_)   // 49152
#define A_N (AROWS*64)         // 3145728
#define BI_N (448*64)          // 28672

struct PrepArgs {
    CvtArgs cvt;
    const void *Wih, *Whh, *Watt, *mWih, *mWhh, *Wmt, *Wme;
    const void *bond, *Wnei, *atom, *Watom;
    float* conv;
    unsigned short *B2t, *WatT, *WGi, *WGh, *WmtT, *WmeT, *XH, *A16, *Bi16;
    const unsigned* amtag;
    int ew_total;
};

__device__ __forceinline__ float ldd(const void* p, size_t i, bool f32){
    return f32 ? ((const float*)p)[i] : b2f(((const bf16*)p)[i]);
}

// prologue elementwise: small-param convert + all weight repacks + XH pad + A16/Bi16 packing
__global__ void __launch_bounds__(256) k_prep(PrepArgs A){
    bool f32 = (*A.amtag == FP32TAG);
    int i = blockIdx.x*256 + (int)threadIdx.x;
    if (i >= A.ew_total) return;
    if (i < CONV_N){
        int s = 0;
        while (i >= A.cvt.ofs[s+1]) s++;
        A.conv[i] = ldd(A.cvt.src[s], i - A.cvt.ofs[s], f32);
        return;
    }
    int i2 = i - CONV_N;
    if (i2 < PREPB_N){
        int kk = i2 % KP;
        int rest = i2 / KP;
        int n = rest % NP;
        int r = rest / NP;
        float v = 0.f;
        if (kk < 200){
            if (n < 600) v = ldd(A.Wih, ((size_t)(r*G3D_ + n))*D_ + kk, f32);
        } else if (kk < 400){
            int j = -1;
            if (n < 400) j = n;
            else if (n >= 600 && n < 800) j = n - 200;
            if (j >= 0) v = ldd(A.Whh, ((size_t)(r*G3D_ + j))*D_ + (kk-200), f32);
        }
        A.B2t[i2] = f2b(v);
        return;
    }
    int i3 = i2 - PREPB_N;
    if (i3 < PREPW_N){
        int kk = i3 % KC;
        int rest = i3 / KC;
        int n = rest % NC;
        int r = rest / NC;
        float v = 0.f;
        if (kk < 200 && n < 200) v = ldd(A.Watt, ((size_t)r*D_ + kk)*D_ + n, f32);
        A.WatT[i3] = f2b(v);
        return;
    }
    int i4 = i3 - PREPW_N;
    if (i4 < PREPG_N){
        // WGi = mWih rows (row-per-output already), WGh = mWhh rows; flat bf16 convert
        int half = i4 / PREPM_N;
        int s = i4 - half*PREPM_N;
        (half ? A.WGh : A.WGi)[s] = f2b(ldd(half ? A.mWhh : A.mWih, s, f32));
        return;
    }
    int i5 = i4 - PREPG_N;
    if (i5 < PREPT_N){
        // WmtT[d*200+k] = Wmt[k*200+d]; source-ordered reads
        int k = i5 / 200, d = i5 % 200;
        A.WmtT[(size_t)d*200 + k] = f2b(ldd(A.Wmt, i5, f32));
        return;
    }
    int i6 = i5 - PREPT_N;
    if (i6 < PREPE_N){
        // WmeT[d*400+k] = Wme[k*200+d], k<400; source-ordered reads
        int k = i6 / 200, d = i6 % 200;
        A.WmeT[(size_t)d*400 + k] = f2b(ldd(A.Wme, i6, f32));
        return;
    }
    int i7 = i6 - PREPE_N;
    if (i7 < XHPAD_N){
        int al = i7 >> 4, j = i7 & 15;
        A.XH[(size_t)al*KP + 400 + j] = 0;
        return;
    }
    int i8 = i7 - XHPAD_N;
    if (i8 < A_N){
        int row = i8 >> 6, k = i8 & 63;
        float v = 0.f;
        if (row < BL_){
            if (k < FA_) v = ldd(A.atom, (size_t)row*FA_ + k, f32);
        } else {
            int rb = row - BL_;
            if (k >= FA_ && k < FA_+FB_) v = ldd(A.bond, (size_t)rb*FB_ + (k-FA_), f32);
        }
        A.A16[i8] = f2b(v);
        return;
    }
    int i9 = i8 - A_N;
    if (i9 < BI_N){
        int n = i9 >> 6, k = i9 & 63;
        float v = 0.f;
        if (n < 200){
            if (k < FA_) v = ldd(A.Watom, (size_t)k*D_ + n, f32);
        } else if (n < 400){
            if (k < FA_+FB_) v = ldd(A.Wnei, (size_t)k*D_ + (n-200), f32);
        }
        A.Bi16[i9] = f2b(v);
    }
}

// MFMA init GEMM: C[49152,448] = A16 @ Bi16^T. Atom rows -> XH h-half (lrelu+b_atom) and
// P16 (+b_nei); bond rows -> Q16. 128x64 tile, K=64 (2 steps).
__global__ void __launch_bounds__(256) k_initmm(const unsigned short* __restrict__ A16,
        const unsigned short* __restrict__ Bi16,
        const void* __restrict__ batom, const void* __restrict__ bnei,
        unsigned short* __restrict__ XH, unsigned short* __restrict__ P16,
        unsigned short* __restrict__ Q16, const unsigned* __restrict__ amtag){
    __shared__ unsigned short As[128][40];
    __shared__ unsigned short Bs[64][40];
    bool f32 = (*amtag == FP32TAG);
    int tid = threadIdx.x;
    int mt = (int)blockIdx.x / 7, nt = (int)blockIdx.x % 7;
    int m0 = mt*128, n0 = nt*64;
    if (m0 >= BL_ && n0 + 64 <= 200) return;   // bond rows x atom-feature cols: all dead
    int lane = tid & 63, wv = tid >> 6;
    int quad = lane >> 4, lm = lane & 15;
    f32x4 acc[2][4];
    #pragma unroll
    for (int a=0;a<2;a++)
        #pragma unroll
        for (int b=0;b<4;b++) acc[a][b] = (f32x4){0.f,0.f,0.f,0.f};
    for (int ks = 0; ks < 2; ks++){
        int r0_ = tid >> 2, c0 = (tid & 3) * 8;
        int r1_ = (tid + 256) >> 2, c1 = ((tid + 256) & 3) * 8;
        uint4 a0 = *(const uint4*)&A16[(size_t)(m0 + r0_)*64 + ks*32 + c0];
        uint4 a1 = *(const uint4*)&A16[(size_t)(m0 + r1_)*64 + ks*32 + c1];
        uint4 b0 = *(const uint4*)&Bi16[(size_t)(n0 + (tid >> 2))*64 + ks*32 + (tid & 3)*8];
        __syncthreads();
        *(uint4*)&As[r0_][c0] = a0;
        *(uint4*)&As[r1_][c1] = a1;
        *(uint4*)&Bs[tid >> 2][(tid & 3)*8] = b0;
        __syncthreads();
        short8 av0 = *(const short8*)&As[wv*32 + lm][quad*8];
        short8 av1 = *(const short8*)&As[wv*32 + 16 + lm][quad*8];
        #pragma unroll
        for (int ns=0; ns<4; ns++){
            short8 bv = *(const short8*)&Bs[ns*16 + lm][quad*8];
            acc[0][ns] = __builtin_amdgcn_mfma_f32_16x16x32_bf16(av0, bv, acc[0][ns], 0,0,0);
            acc[1][ns] = __builtin_amdgcn_mfma_f32_16x16x32_bf16(av1, bv, acc[1][ns], 0,0,0);
        }
    }
    #pragma unroll
    for (int ms=0; ms<2; ms++)
      #pragma unroll
      for (int ns=0; ns<4; ns++){
        int n = n0 + ns*16 + lm;
        #pragma unroll
        for (int i=0;i<4;i++){
            int row = m0 + wv*32 + ms*16 + quad*4 + i;
            float v = acc[ms][ns][i];
            if (row < BL_){
                if (n < 200){
                    XH[(size_t)row*KP + 200 + n] = f2b(lreluf(v + ldd(batom, n, f32)));
                } else if (n < 400){
                    P16[(size_t)row*D_ + (n-200)] = f2b(v + ldd(bnei, n-200, f32));
                }
            } else if (n >= 200 && n < 400){
                Q16[(size_t)(row-BL_)*D_ + (n-200)] = f2b(v);
            }
        }
      }
}

// attention (all rounds): softmax + weighted neighbor sum -> bf16 wnei (stride KC, zero pad).
// XCD-locality swizzle: mol = bid&127. r0: compile-time-unrolled n (no div, no
// runtime-indexed idxn), fused Wab dot into the s_nei fill, interleaved shfl reductions.
__global__ void __launch_bounds__(256) k_attn(
        const unsigned short* __restrict__ cur16, const unsigned short* __restrict__ XH,
        const float* __restrict__ s1, const float* __restrict__ tb,
        const int* __restrict__ adl, const int* __restrict__ bdl,
        const unsigned short* __restrict__ P16, const unsigned short* __restrict__ Q16,
        const float* __restrict__ W_align, const float* __restrict__ b_align, int r,
        unsigned short* __restrict__ wnei, float* __restrict__ wsum){
    int bid = blockIdx.x;
    int mol = bid & (B_-1), chunk = bid >> 7;
    int wv = threadIdx.x >> 6, lane = threadIdx.x & 63;
    int al = mol*L_ + chunk*4 + wv;
    __shared__ float s_nei[4][N_][D_];

    int idxn[N_]; bool pad[N_];
    #pragma unroll
    for (int n=0;n<N_;n++){ idxn[n] = adl[al*N_ + n]; pad[n] = (idxn[n] == L_-1); }

    float s2[N_];
    float s1v;
    if (r == 0){
        const float* Wab = W_align + D_;
        float acc[N_+1];
        #pragma unroll
        for (int n=0;n<N_+1;n++) acc[n] = 0.f;
        #pragma unroll
        for (int n=0;n<N_;n++){
            int bd = bdl[al*N_ + n];
            const unsigned short* Prow = P16 + ((size_t)mol*L_ + idxn[n])*D_;
            const unsigned short* Qrow = Q16 + ((size_t)mol*MB_ + bd)*D_;
            for (int d=lane; d<D_; d+=64){
                float v = lreluf(bu2f(Prow[d]) + bu2f(Qrow[d]));
                s_nei[wv][n][d] = v;
                acc[n] += v * Wab[d];
            }
        }
        for (int d=lane; d<D_; d+=64)
            acc[N_] += bu2f(XH[(size_t)al*KP + 200 + d]) * W_align[d];
        #pragma unroll
        for (int o=32;o>0;o>>=1)
            #pragma unroll
            for (int n=0;n<N_+1;n++) acc[n] += __shfl_xor(acc[n],o);
        #pragma unroll
        for (int n=0;n<N_;n++) s2[n] = acc[n];
        s1v = acc[N_];
    } else {
        float tmp = 0.f;
        if (lane < N_) tmp = tb[mol*L_ + idxn[lane]];
        #pragma unroll
        for (int n=0;n<N_;n++) s2[n] = __shfl(tmp, n);
        s1v = s1[al];
    }

    float bav = b_align[r];
    float a[N_]; float mx = -1e30f;
    #pragma unroll
    for (int n=0;n<N_;n++){
        float v = lreluf(s1v + s2[n] + bav);
        if (pad[n]) v += NEGV;
        a[n] = v; mx = fmaxf(mx, v);
    }
    float w[N_]; float se = 0.f;
    #pragma unroll
    for (int n=0;n<N_;n++){ float e = expf(a[n]-mx); w[n]=e; se += e; }
    float inv = 1.f/se; float wsv = 0.f;
    #pragma unroll
    for (int n=0;n<N_;n++){ w[n] = pad[n] ? 0.f : w[n]*inv; wsv += w[n]; }

    if (r == 0){
        for (int d=lane; d<D_; d+=64){
            float acc = 0.f;
            #pragma unroll
            for (int n=0;n<N_;n++) acc += w[n] * s_nei[wv][n][d];
            wnei[(size_t)al*KC + d] = f2b(acc);
        }
    } else {
        for (int d=lane; d<D_; d+=64){
            float acc = 0.f;
            #pragma unroll
            for (int n=0;n<N_;n++) acc += w[n] * bu2f(cur16[((size_t)mol*L_ + idxn[n])*KC + d]);
            wnei[(size_t)al*KC + d] = f2b(acc);
        }
    }
    if (lane < 24) wnei[(size_t)al*KC + 200 + lane] = 0;
    if (lane==0) wsum[al] = wsv;
}

// MFMA ctx GEMM: elu(wnei[16384,KC] @ WatT[r]^T + wsum*bias) -> XH x-half. 128x64 tile.
__global__ void __launch_bounds__(256) k_ctxmfma(const unsigned short* __restrict__ Wn,
        const float* __restrict__ wsum, const unsigned short* __restrict__ WatT,
        const float* __restrict__ bias, int r, unsigned short* __restrict__ XH){
    __shared__ unsigned short As[128][40];
    __shared__ unsigned short Bs[64][40];
    int tid = threadIdx.x;
    int m0 = ((int)blockIdx.x & 127) * 128;
    int n0 = ((int)blockIdx.x >> 7) * 64;
    const unsigned short* Bt = WatT + (size_t)r*NC*KC;
    int lane = tid & 63, wv = tid >> 6;
    int quad = lane >> 4, lm = lane & 15;
    f32x4 acc[2][4];
    #pragma unroll
    for (int a=0;a<2;a++)
        #pragma unroll
        for (int b=0;b<4;b++) acc[a][b] = (f32x4){0.f,0.f,0.f,0.f};
    for (int ks = 0; ks < 7; ks++){
        int r0_ = tid >> 2, c0 = (tid & 3) * 8;
        int r1_ = (tid + 256) >> 2, c1 = ((tid + 256) & 3) * 8;
        uint4 a0 = *(const uint4*)&Wn[(size_t)(m0 + r0_)*KC + ks*32 + c0];
        uint4 a1 = *(const uint4*)&Wn[(size_t)(m0 + r1_)*KC + ks*32 + c1];
        uint4 b0 = *(const uint4*)&Bt[(size_t)(n0 + (tid >> 2))*KC + ks*32 + (tid & 3)*8];
        __syncthreads();
        *(uint4*)&As[r0_][c0] = a0;
        *(uint4*)&As[r1_][c1] = a1;
        *(uint4*)&Bs[tid >> 2][(tid & 3)*8] = b0;
        __syncthreads();
        short8 av0 = *(const short8*)&As[wv*32 + lm][quad*8];
        short8 av1 = *(const short8*)&As[wv*32 + 16 + lm][quad*8];
        #pragma unroll
        for (int ns=0; ns<4; ns++){
            short8 bv = *(const short8*)&Bs[ns*16 + lm][quad*8];
            acc[0][ns] = __builtin_amdgcn_mfma_f32_16x16x32_bf16(av0, bv, acc[0][ns], 0,0,0);
            acc[1][ns] = __builtin_amdgcn_mfma_f32_16x16x32_bf16(av1, bv, acc[1][ns], 0,0,0);
        }
    }
    #pragma unroll
    for (int ms=0; ms<2; ms++)
      #pragma unroll
      for (int ns=0; ns<4; ns++){
        int n = n0 + ns*16 + lm;
        if (n < 200){
            float bv = bias[r*D_ + n];
            #pragma unroll
            for (int i=0;i<4;i++){
                int row = m0 + wv*32 + ms*16 + quad*4 + i;
                float v = acc[ms][ns][i] + wsum[row]*bv;
                XH[(size_t)row*KP + n] = f2b(eluf(v));
            }
        }
      }
}

// MFMA gate GEMM: C[16384,NP] = XH @ B2t[r]^T. 128x64 tiles (13 n-tiles cover the 800
// live cols; tail waste 32 vs 96 with 128-wide tiles) -> grid 128x13 = 1664 blocks
// (~2x TLP of the 896-block 128x128 version; B panel L2-resident). C stride stays NP;
// cols 800-831 get garbage that k_gru2 never reads.
__global__ void __launch_bounds__(256) k_gemm(const unsigned short* __restrict__ XH,
        const unsigned short* __restrict__ B2t, unsigned short* __restrict__ C, int r){
    __shared__ unsigned short As[128][40];
    __shared__ unsigned short Bs[64][40];
    int tid = threadIdx.x;
    int m0 = ((int)blockIdx.x & 127) * 128;
    int n0 = ((int)blockIdx.x >> 7) * 64;
    const unsigned short* Bt = B2t + (size_t)r*NP*KP;
    int lane = tid & 63, wv = tid >> 6;
    int quad = lane >> 4, lm = lane & 15;
    f32x4 acc[2][4];
    #pragma unroll
    for (int a=0;a<2;a++)
        #pragma unroll
        for (int b=0;b<4;b++) acc[a][b] = (f32x4){0.f,0.f,0.f,0.f};
    for (int ks = 0; ks < 13; ks++){
        int r0_ = tid >> 2, c0 = (tid & 3) * 8;
        int r1_ = (tid + 256) >> 2, c1 = ((tid + 256) & 3) * 8;
        uint4 a0 = *(const uint4*)&XH[(size_t)(m0 + r0_)*KP + ks*32 + c0];
        uint4 a1 = *(const uint4*)&XH[(size_t)(m0 + r1_)*KP + ks*32 + c1];
        uint4 b0 = *(const uint4*)&Bt[(size_t)(n0 + r0_ - ((r0_ >= 64) ? 64 : 0))*KP + ks*32 + c0];
        // threads 0-255 cover A rows 0-63 (r0_) and 64-127 (r1_); B needs only 64 rows:
        // first 256 threads' r0_ in [0,64) load B rows n0+r0_ directly.
        __syncthreads();
        *(uint4*)&As[r0_][c0] = a0;
        *(uint4*)&As[r1_][c1] = a1;
        if (r0_ < 64) *(uint4*)&Bs[r0_][c0] = b0;
        __syncthreads();
        short8 av0 = *(const short8*)&As[wv*32 + lm][quad*8];
        short8 av1 = *(const short8*)&As[wv*32 + 16 + lm][quad*8];
        #pragma unroll
        for (int ns=0; ns<4; ns++){
            short8 bv = *(const short8*)&Bs[ns*16 + lm][quad*8];
            acc[0][ns] = __builtin_amdgcn_mfma_f32_16x16x32_bf16(av0, bv, acc[0][ns], 0,0,0);
            acc[1][ns] = __builtin_amdgcn_mfma_f32_16x16x32_bf16(av1, bv, acc[1][ns], 0,0,0);
        }
    }
    #pragma unroll
    for (int ms=0; ms<2; ms++)
      #pragma unroll
      for (int ns=0; ns<4; ns++)
        #pragma unroll
        for (int i=0;i<4;i++){
            int row = m0 + wv*32 + ms*16 + quad*4 + i;
            C[(size_t)row*NP + n0 + ns*16 + lm] = f2b(acc[ms][ns][i]);
        }
}

// GRU combine, wave-per-atom; GRU state lives in XH h-half (bf16). Writes cur16;
// fuses next-round s1/tb dots (r<2) or curdot (r==2).
__global__ void __launch_bounds__(256) k_gru2(const unsigned short* __restrict__ C,
        unsigned short* __restrict__ XH, unsigned short* __restrict__ cur16,
        const float* __restrict__ bih, const float* __restrict__ bhh,
        const float* __restrict__ W_align, const float* __restrict__ Wma, int r,
        float* __restrict__ s1, float* __restrict__ tb, float* __restrict__ curdot){
    int wv = threadIdx.x >> 6, lane = threadIdx.x & 63;
    int al = blockIdx.x*4 + wv;
    size_t base = (size_t)al*NP;
    const float* bi = bih + r*G3D_;
    const float* bh = bhh + r*G3D_;
    const float* Wa = W_align + (r+1)*2*D_;   // dereferenced only when r<2
    bool last = (r == R_-1);
    float a1 = 0.f, a2 = 0.f;
    for (int j = lane; j < D_; j += 64){
        float rsum = bu2f(C[base + j]);
        float zsum = bu2f(C[base + 200 + j]);
        float gin  = bu2f(C[base + 400 + j]);
        float ghn  = bu2f(C[base + 600 + j]);
        float rr = sigmf(rsum + bi[j] + bh[j]);
        float zz = sigmf(zsum + bi[D_+j] + bh[D_+j]);
        float nn = tanhf(gin + bi[2*D_+j] + rr*(ghn + bh[2*D_+j]));
        size_t hx = (size_t)al*KP + 200 + j;
        float hv = bu2f(XH[hx]);
        float hn = (1.f-zz)*nn + zz*hv;
        XH[hx] = f2b(hn);
        float cv = fmaxf(hn, 0.f);
        cur16[(size_t)al*KC + j] = f2b(cv);
        if (last){
            a1 += cv * Wma[D_+j];
        } else {
            a1 += cv * Wa[j];
            a2 += cv * Wa[D_+j];
        }
    }
    if (lane < 24) cur16[(size_t)al*KC + 200 + lane] = 0;
    for (int o=32;o>0;o>>=1){ a1 += __shfl_xor(a1,o); a2 += __shfl_xor(a2,o); }
    if (lane==0){
        if (last) curdot[al] = a1;
        else { s1[al] = a1; tb[al] = a2; }
    }
}

__device__ __forceinline__ float brSum(float v, float* s_red){
    for (int o=32;o>0;o>>=1) v += __shfl_xor(v,o);
    int lane = threadIdx.x & 63, wid = threadIdx.x >> 6;
    __syncthreads();
    if (lane==0) s_red[wid] = v;
    __syncthreads();
    float r = 0.f;
    int nw = blockDim.x >> 6;
    for (int i=0;i<nw;i++) r += s_red[i];
    return r;
}

// 200-elem dot of a bf16 row (25x uint4) with an LDS f32 vector (16B-aligned)
__device__ __forceinline__ float dot200(const unsigned short* __restrict__ wrow,
                                        const float* __restrict__ v){
    const uint4* wp = (const uint4*)wrow;
    float a0=0.f, a1=0.f;
    #pragma unroll
    for (int kk=0; kk<25; kk++){
        uint4 u = wp[kk];
        f32x4 A = *(const f32x4*)&v[8*kk];
        f32x4 Bv = *(const f32x4*)&v[8*kk+4];
        a0 += A[0]*lo2f(u.x) + A[1]*hi2f(u.x);
        a1 += A[2]*lo2f(u.y) + A[3]*hi2f(u.y);
        a0 += Bv[0]*lo2f(u.z) + Bv[1]*hi2f(u.z);
        a1 += Bv[2]*lo2f(u.w) + Bv[3]*hi2f(u.w);
    }
    return a0 + a1;
}

// molecule phase, 512 threads (8 waves), phase-minimized (4 barriers/t-iter).
// Waves 0-3: full softmax redundantly in-register + wc; waves 4-7: gh GEMV concurrently.
// __launch_bounds__(512,1): only 128 blocks exist (1/CU), so do NOT let the compiler
// cap VGPR at 128 for a useless 2-blocks/CU target (R6: cap -> 1MB spill -> 73us).
// sched_barrier(0) after each GEMV row pins the live set (no cross-row load hoisting).
__global__ void __launch_bounds__(512, 1) k_mol(const unsigned short* __restrict__ cur16,
    const float* __restrict__ curdot, const float* __restrict__ atom_mask,
    const float* __restrict__ Wma, const float* __restrict__ bma,
    const unsigned short* __restrict__ WmtT, const float* __restrict__ bmt,
    const unsigned short* __restrict__ WGi, const unsigned short* __restrict__ WGh,
    const float* __restrict__ mbih, const float* __restrict__ mbhh,
    const unsigned short* __restrict__ WmeT, const float* __restrict__ bme,
    const float* __restrict__ Wout, const float* __restrict__ bout,
    void* __restrict__ out, const unsigned* __restrict__ amtag){
    int b = blockIdx.x, tid = threadIdx.x;
    int wv = tid >> 6, lane = tid & 63;
    int dq = tid & 255, cq = tid >> 8;
    __shared__ unsigned short s_cur[L_*KC];
    __shared__ float s_am[L_], s_neg[L_], s_cd[L_];
    __shared__ float s_wp[4][L_];      // per-wave private softmax weights
    __shared__ __attribute__((aligned(16))) float s_mf[D_];
    __shared__ __attribute__((aligned(16))) float s_act[D_];
    __shared__ __attribute__((aligned(16))) float s_wc[D_];
    __shared__ __attribute__((aligned(16))) float s_ctx[D_];
    __shared__ __attribute__((aligned(16))) float s_mf2[2*D_];
    __shared__ float s_gi[G3D_], s_gh[G3D_];
    __shared__ float s_wma[D_], s_bmt[D_], s_bi[G3D_], s_bh[G3D_];
    __shared__ float s_part[2][256];
    __shared__ float s_red[8];
    __shared__ float s_wsm;
    const uint4* src = (const uint4*)(cur16 + (size_t)b*L_*KC);
    for (int i = tid; i < L_*KC/8; i += 512) ((uint4*)s_cur)[i] = src[i];
    if (tid < L_){
        float am = atom_mask[b*L_ + tid];
        s_am[tid] = am;
        s_neg[tid] = (am == 0.f) ? NEGV : 0.f;
        s_cd[tid] = curdot[b*L_ + tid];
    }
    if (tid < D_){ s_wma[tid] = Wma[tid]; s_bmt[tid] = bmt[tid]; }
    for (int j = tid; j < G3D_; j += 512){
        s_bi[j] = mbih[j];
        s_bh[j] = mbhh[j];
    }
    __syncthreads();
    {   // mol_feature = sum_l am[l]*cur[l,:]
        float a0 = 0.f, a1 = 0.f;
        if (dq < D_)
            for (int l=cq*64; l<cq*64+64; l+=2){
                a0 += bu2f(s_cur[l*KC + dq]) * s_am[l];
                a1 += bu2f(s_cur[(l+1)*KC + dq]) * s_am[l+1];
            }
        s_part[cq][dq] = a0 + a1;
        __syncthreads();
        if (tid < D_){
            float v = s_part[0][tid] + s_part[1][tid];
            s_mf[tid] = v; s_act[tid] = fmaxf(v, 0.f);
        }
        __syncthreads();
    }
    float bma0 = bma[0];
    #pragma unroll 1
    for (int t=0;t<T_;t++){
        if (wv < 4){
            // ---- redundant in-wave softmax (no block reductions) ----
            float a = s_act[lane]*s_wma[lane] + s_act[lane+64]*s_wma[lane+64];
            a += s_act[lane+128]*s_wma[lane+128];
            if (lane < 8) a += s_act[lane+192]*s_wma[lane+192];
            #pragma unroll
            for (int o=32;o>0;o>>=1) a += __shfl_xor(a,o);       // s1v
            float sc0 = lreluf(a + s_cd[lane] + bma0) + s_neg[lane];
            float sc1 = lreluf(a + s_cd[lane+64] + bma0) + s_neg[lane+64];
            float m = fmaxf(sc0, sc1);
            #pragma unroll
            for (int o=32;o>0;o>>=1) m = fmaxf(m, __shfl_xor(m,o));
            float e0 = expf(sc0 - m), e1 = expf(sc1 - m);
            float s = e0 + e1;
            #pragma unroll
            for (int o=32;o>0;o>>=1) s += __shfl_xor(s,o);
            float inv = 1.f/s;
            float w0 = e0*inv*s_am[lane], w1 = e1*inv*s_am[lane+64];
            float ws = w0 + w1;
            #pragma unroll
            for (int o=32;o>0;o>>=1) ws += __shfl_xor(ws,o);
            s_wp[wv][lane] = w0; s_wp[wv][lane+64] = w1;
            if (tid == 0) s_wsm = ws;
            // ---- wc[d] = sum_l w[l]*cur[l][d]  (d = tid, own wave's w copy) ----
            if (tid < D_){
                float acc = 0.f;
                #pragma unroll 16
                for (int l=0; l<L_; l++)
                    acc += s_wp[wv][l] * bu2f(s_cur[l*KC + tid]);
                s_wc[tid] = acc;
            }
        } else {
            // ---- gh GEMV (depends only on s_mf): 600 rows over 256 threads ----
            int h = tid - 256;
            #pragma unroll 1
            for (int rr=0; rr<3; rr++){
                int row = h + rr*256;
                if (row < G3D_)
                    s_gh[row] = dot200(WGh + (size_t)row*D_, s_mf);
                __builtin_amdgcn_sched_barrier(0);   // pin live set per row
            }
        }
        __syncthreads();   // #1: s_wc, s_gh, s_wsm ready
        if (tid < D_){
            float acc = dot200(WmtT + (size_t)tid*D_, s_wc);
            s_ctx[tid] = eluf(acc + s_wsm * s_bmt[tid]);
        }
        __syncthreads();   // #2: s_ctx ready
        {
            #pragma unroll 1
            for (int rr=0; rr<2; rr++){
                int row = tid + rr*512;
                if (row < G3D_)
                    s_gi[row] = dot200(WGi + (size_t)row*D_, s_ctx);
                __builtin_amdgcn_sched_barrier(0);   // pin live set per row
            }
        }
        __syncthreads();   // #3: s_gi ready
        if (tid < D_){
            int d = tid;
            float rr = sigmf(s_gi[d] + s_bi[d] + s_gh[d] + s_bh[d]);
            float zz = sigmf(s_gi[D_+d] + s_bi[D_+d] + s_gh[D_+d] + s_bh[D_+d]);
            float nn = tanhf(s_gi[2*D_+d] + s_bi[2*D_+d] + rr*(s_gh[2*D_+d] + s_bh[2*D_+d]));
            float nm = (1.f-zz)*nn + zz*s_mf[d];
            s_mf[d] = nm; s_act[d] = fmaxf(nm, 0.f);
        }
        __syncthreads();   // #4: s_mf/s_act for next t (or epilogue)
        __builtin_amdgcn_sched_barrier(0);           // no cross-t pipelining
    }
    const float dd = (float)(R_ - 2);
    if (tid < 2*D_) s_mf2[tid] = (tid < D_) ? s_mf[tid] : s_mf[tid - D_] + dd;
    __syncthreads();
    float p2 = 0.f;
    if (tid < D_){
        const uint4* wp = (const uint4*)(WmeT + (size_t)tid*400);
        float a0=0.f, a1=0.f;
        #pragma unroll
        for (int kk=0; kk<50; kk++){
            uint4 u = wp[kk];
            f32x4 wA = *(const f32x4*)&s_mf2[8*kk];
            f32x4 wB = *(const f32x4*)&s_mf2[8*kk+4];
            a0 += wA[0]*lo2f(u.x) + wA[1]*hi2f(u.x);
            a1 += wA[2]*lo2f(u.y) + wA[3]*hi2f(u.y);
            a0 += wB[0]*lo2f(u.z) + wB[1]*hi2f(u.z);
            a1 += wB[2]*lo2f(u.w) + wB[3]*hi2f(u.w);
        }
        p2 = (a0 + a1 + bme[tid]) * Wout[tid];
    }
    float o = brSum(p2, s_red);
    if (tid==0){
        o += bout[0];
        if (*amtag == FP32TAG) ((float*)out)[b] = o;
        else ((bf16*)out)[b] = __float2bfloat16(o);
    }
}

extern "C" void kernel_launch(void* const* d_in, const int* in_sizes, int n_in,
                              void* d_out, int out_size, void* d_ws, size_t ws_size,
                              hipStream_t stream) {
    const int* adl = (const int*)d_in[2];
    const int* bdl = (const int*)d_in[3];
    const unsigned* amtag = (const unsigned*)d_in[4];

    static const int srcidx[NSEG] = {4,9,10,12,15,16,17,18,20,23,24,26,27,28};
    static const int segsz[NSEG]  = {16384,1200,3,600,1800,1800,400,1,200,600,600,200,200,1};
    CvtArgs ca;
    int ofs[NSEG+1]; ofs[0] = 0;
    for (int i=0;i<NSEG;i++){ ca.src[i] = d_in[srcidx[i]]; ca.ofs[i] = ofs[i]; ofs[i+1] = ofs[i] + segsz[i]; }
    ca.ofs[NSEG] = ofs[NSEG];   // 23989

    // ws layout. ~54 MB total.
    float* ws   = (float*)d_ws;
    float* conv = ws;                                            // 24000 fl
    unsigned short* XH    = (unsigned short*)(conv + 24000);     // BL_*KP sh
    unsigned short* B2t   = XH + (size_t)BL_*KP;                 // PREPB_N sh
    unsigned short* WatT  = B2t + PREPB_N;                       // PREPW_N sh
    unsigned short* WGi   = WatT + PREPW_N;                      // PREPM_N sh
    unsigned short* WGh   = WGi + PREPM_N;                       // PREPM_N sh
    unsigned short* WmtT  = WGh + PREPM_N;                       // PREPT_N sh
    unsigned short* WmeT  = WmtT + PREPT_N;                      // PREPE_N sh
    unsigned short* Bi16  = WmeT + PREPE_N;                      // BI_N sh
    unsigned short* cur16 = Bi16 + BI_N;                         // BL_*KC sh
    unsigned short* creg  = cur16 + (size_t)BL_*KC;              // C region: BL_*NP sh
    unsigned short* C = creg;
    unsigned short* A16  = creg;                                 // overlay (dead before wnei)
    unsigned short* wnei = creg;                                 // BL_*KC sh overlay
    unsigned short* Q16  = creg + (size_t)BL_*KC;                // B_*MB_*D_ sh overlay
    unsigned short* P16  = Q16 + (size_t)B_*MB_*D_;              // BL_*D_ sh overlay
    float* s1     = (float*)(creg + (size_t)BL_*NP);
    float* tb     = s1 + BL_;
    float* wsum   = tb + BL_;
    float* curdot = wsum + BL_;

    const float* c_amask = conv + ofs[0];
    const float* c_Walign= conv + ofs[1];
    const float* c_balign= conv + ofs[2];
    const float* c_batt  = conv + ofs[3];
    const float* c_bih   = conv + ofs[4];
    const float* c_bhh   = conv + ofs[5];
    const float* c_Wma   = conv + ofs[6];
    const float* c_bma   = conv + ofs[7];
    const float* c_bmt   = conv + ofs[8];
    const float* c_mbih  = conv + ofs[9];
    const float* c_mbhh  = conv + ofs[10];
    const float* c_bme   = conv + ofs[11];
    const float* c_Wout  = conv + ofs[12];
    const float* c_bout  = conv + ofs[13];

    PrepArgs A;
    A.cvt = ca;
    A.Wih = d_in[13]; A.Whh = d_in[14]; A.Watt = d_in[11];
    A.mWih = d_in[21]; A.mWhh = d_in[22]; A.Wmt = d_in[19]; A.Wme = d_in[25];
    A.bond = d_in[1]; A.Wnei = d_in[7]; A.atom = d_in[0]; A.Watom = d_in[5];
    A.conv = conv;
    A.B2t = B2t; A.WatT = WatT; A.WGi = WGi; A.WGh = WGh; A.WmtT = WmtT; A.WmeT = WmeT;
    A.XH = XH; A.A16 = A16; A.Bi16 = Bi16;
    A.amtag = amtag;
    A.ew_total = CONV_N + PREPB_N + PREPW_N + PREPG_N + PREPT_N + PREPE_N
               + XHPAD_N + A_N + BI_N;   // 5110773

    k_prep<<<(A.ew_total + 255)/256, 256, 0, stream>>>(A);
    k_initmm<<<(AROWS/128)*7, 256, 0, stream>>>(A16, Bi16, d_in[6], d_in[8],
                                                XH, P16, Q16, amtag);

    for (int r=0; r<R_; r++){
        k_attn<<<BL_/4, 256, 0, stream>>>(cur16, XH, s1, tb, adl, bdl, P16, Q16,
                                          c_Walign, c_balign, r, wnei, wsum);
        k_ctxmfma<<<(BL_/128)*(NC/64), 256, 0, stream>>>(wnei, wsum, WatT, c_batt, r, XH);
        k_gemm<<<(BL_/128)*NT2, 256, 0, stream>>>(XH, B2t, C, r);
        k_gru2<<<BL_/4, 256, 0, stream>>>(C, XH, cur16, c_bih, c_bhh,
                                          c_Walign, c_Wma, r, s1, tb, curdot);
    }

    k_mol<<<B_, 512, 0, stream>>>(cur16, curdot, c_amask, c_Wma, c_bma, WmtT, c_bmt,
                                  WGi, WGh, c_mbih, c_mbhh, WmeT, c_bme, c_Wout, c_bout,
                                  d_out, amtag);
}

// Round 13
// 399.046 us; speedup vs baseline: 1.2880x; 1.0152x over previous
//
#include <hip/hip_runtime.h>
#include <hip/hip_bf16.h>
#include <math.h>
#include <string.h>

#define B_ 128
#define L_ 128
#define N_ 6
#define FA_ 39
#define FB_ 10
#define D_ 200
#define MB_ 256
#define R_ 3
#define T_ 2
#define NEGV -9e8f
#define BL_ (B_*L_)        // 16384
#define G3D_ (3*D_)        // 600
#define FP32TAG 0x3F800000u
#define KP 416             // padded K for gate GEMM
#define NP 896             // padded N for gate GEMM (C stride; cols 800+ dead)
#define NT2 13             // k_gemm n-tiles of 64 (13*64=832 >= 800 live cols)
#define KC 224             // padded K for ctx GEMM (7*32)
#define NC 256             // padded N for ctx GEMM

typedef __hip_bfloat16 bf16;
typedef __attribute__((ext_vector_type(8))) short short8;
typedef __attribute__((ext_vector_type(4))) float f32x4;

__device__ __forceinline__ float b2f(const bf16 x){ return __bfloat162float(x); }
__device__ __forceinline__ unsigned short f2b(float v){ bf16 t = __float2bfloat16(v); return *reinterpret_cast<unsigned short*>(&t); }
__device__ __forceinline__ float bu2f(unsigned short u){ unsigned x = ((unsigned)u)<<16; float f; memcpy(&f,&x,4); return f; }
__device__ __forceinline__ float lo2f(unsigned x){ unsigned y = x<<16; float f; memcpy(&f,&y,4); return f; }
__device__ __forceinline__ float hi2f(unsigned x){ unsigned y = x & 0xffff0000u; float f; memcpy(&f,&y,4); return f; }
__device__ __forceinline__ float lreluf(float x){ return x>=0.f ? x : 0.01f*x; }
__device__ __forceinline__ float eluf(float x){ return x>0.f ? x : expm1f(x); }
__device__ __forceinline__ float sigmf(float x){ return 1.f/(1.f+expf(-x)); }

#define NSEG 14
struct CvtArgs { const void* src[NSEG]; int ofs[NSEG+1]; };

#define PREPB_N (R_*NP*KP)     // 1118208
#define PREPW_N (R_*NC*KC)     // 172032
#define PREPM_N (D_*G3D_)      // 120000 (per matrix)
#define PREPG_N (2*PREPM_N)    // 240000 (WGi + WGh flat bf16)
#define PREPT_N 40000          // WmtT [d][k]
#define PREPE_N 80000          // WmeT [d][k0..399]
#define CONV_N 23989
#define XHPAD_N (BL_*16)       // 262144
#define AROWS (BL_ + B_*MB_)   // 49152
#define A_N (AROWS*64)         // 3145728
#define BI_N (448*64)          // 28672

struct PrepArgs {
    CvtArgs cvt;
    const void *Wih, *Whh, *Watt, *mWih, *mWhh, *Wmt, *Wme;
    const void *bond, *Wnei, *atom, *Watom;
    float* conv;
    unsigned short *B2t, *WatT, *WGi, *WGh, *WmtT, *WmeT, *XH, *A16, *Bi16;
    const unsigned* amtag;
    int ew_total;
};

__device__ __forceinline__ float ldd(const void* p, size_t i, bool f32){
    return f32 ? ((const float*)p)[i] : b2f(((const bf16*)p)[i]);
}

// prologue elementwise: small-param convert + all weight repacks + XH pad + A16/Bi16 packing
__global__ void __launch_bounds__(256) k_prep(PrepArgs A){
    bool f32 = (*A.amtag == FP32TAG);
    int i = blockIdx.x*256 + (int)threadIdx.x;
    if (i >= A.ew_total) return;
    if (i < CONV_N){
        int s = 0;
        while (i >= A.cvt.ofs[s+1]) s++;
        A.conv[i] = ldd(A.cvt.src[s], i - A.cvt.ofs[s], f32);
        return;
    }
    int i2 = i - CONV_N;
    if (i2 < PREPB_N){
        int kk = i2 % KP;
        int rest = i2 / KP;
        int n = rest % NP;
        int r = rest / NP;
        float v = 0.f;
        if (kk < 200){
            if (n < 600) v = ldd(A.Wih, ((size_t)(r*G3D_ + n))*D_ + kk, f32);
        } else if (kk < 400){
            int j = -1;
            if (n < 400) j = n;
            else if (n >= 600 && n < 800) j = n - 200;
            if (j >= 0) v = ldd(A.Whh, ((size_t)(r*G3D_ + j))*D_ + (kk-200), f32);
        }
        A.B2t[i2] = f2b(v);
        return;
    }
    int i3 = i2 - PREPB_N;
    if (i3 < PREPW_N){
        int kk = i3 % KC;
        int rest = i3 / KC;
        int n = rest % NC;
        int r = rest / NC;
        float v = 0.f;
        if (kk < 200 && n < 200) v = ldd(A.Watt, ((size_t)r*D_ + kk)*D_ + n, f32);
        A.WatT[i3] = f2b(v);
        return;
    }
    int i4 = i3 - PREPW_N;
    if (i4 < PREPG_N){
        // WGi = mWih rows (row-per-output already), WGh = mWhh rows; flat bf16 convert
        int half = i4 / PREPM_N;
        int s = i4 - half*PREPM_N;
        (half ? A.WGh : A.WGi)[s] = f2b(ldd(half ? A.mWhh : A.mWih, s, f32));
        return;
    }
    int i5 = i4 - PREPG_N;
    if (i5 < PREPT_N){
        // WmtT[d*200+k] = Wmt[k*200+d]; source-ordered reads
        int k = i5 / 200, d = i5 % 200;
        A.WmtT[(size_t)d*200 + k] = f2b(ldd(A.Wmt, i5, f32));
        return;
    }
    int i6 = i5 - PREPT_N;
    if (i6 < PREPE_N){
        // WmeT[d*400+k] = Wme[k*200+d], k<400; source-ordered reads
        int k = i6 / 200, d = i6 % 200;
        A.WmeT[(size_t)d*400 + k] = f2b(ldd(A.Wme, i6, f32));
        return;
    }
    int i7 = i6 - PREPE_N;
    if (i7 < XHPAD_N){
        int al = i7 >> 4, j = i7 & 15;
        A.XH[(size_t)al*KP + 400 + j] = 0;
        return;
    }
    int i8 = i7 - XHPAD_N;
    if (i8 < A_N){
        int row = i8 >> 6, k = i8 & 63;
        float v = 0.f;
        if (row < BL_){
            if (k < FA_) v = ldd(A.atom, (size_t)row*FA_ + k, f32);
        } else {
            int rb = row - BL_;
            if (k >= FA_ && k < FA_+FB_) v = ldd(A.bond, (size_t)rb*FB_ + (k-FA_), f32);
        }
        A.A16[i8] = f2b(v);
        return;
    }
    int i9 = i8 - A_N;
    if (i9 < BI_N){
        int n = i9 >> 6, k = i9 & 63;
        float v = 0.f;
        if (n < 200){
            if (k < FA_) v = ldd(A.Watom, (size_t)k*D_ + n, f32);
        } else if (n < 400){
            if (k < FA_+FB_) v = ldd(A.Wnei, (size_t)k*D_ + (n-200), f32);
        }
        A.Bi16[i9] = f2b(v);
    }
}

// MFMA init GEMM: C[49152,448] = A16 @ Bi16^T. Atom rows -> XH h-half (lrelu+b_atom) and
// P16 (+b_nei); bond rows -> Q16. 128x64 tile, K=64 (2 steps).
__global__ void __launch_bounds__(256) k_initmm(const unsigned short* __restrict__ A16,
        const unsigned short* __restrict__ Bi16,
        const void* __restrict__ batom, const void* __restrict__ bnei,
        unsigned short* __restrict__ XH, unsigned short* __restrict__ P16,
        unsigned short* __restrict__ Q16, const unsigned* __restrict__ amtag){
    __shared__ unsigned short As[128][40];
    __shared__ unsigned short Bs[64][40];
    bool f32 = (*amtag == FP32TAG);
    int tid = threadIdx.x;
    int mt = (int)blockIdx.x / 7, nt = (int)blockIdx.x % 7;
    int m0 = mt*128, n0 = nt*64;
    if (m0 >= BL_ && n0 + 64 <= 200) return;   // bond rows x atom-feature cols: all dead
    int lane = tid & 63, wv = tid >> 6;
    int quad = lane >> 4, lm = lane & 15;
    f32x4 acc[2][4];
    #pragma unroll
    for (int a=0;a<2;a++)
        #pragma unroll
        for (int b=0;b<4;b++) acc[a][b] = (f32x4){0.f,0.f,0.f,0.f};
    for (int ks = 0; ks < 2; ks++){
        int r0_ = tid >> 2, c0 = (tid & 3) * 8;
        int r1_ = (tid + 256) >> 2, c1 = ((tid + 256) & 3) * 8;
        uint4 a0 = *(const uint4*)&A16[(size_t)(m0 + r0_)*64 + ks*32 + c0];
        uint4 a1 = *(const uint4*)&A16[(size_t)(m0 + r1_)*64 + ks*32 + c1];
        uint4 b0 = *(const uint4*)&Bi16[(size_t)(n0 + (tid >> 2))*64 + ks*32 + (tid & 3)*8];
        __syncthreads();
        *(uint4*)&As[r0_][c0] = a0;
        *(uint4*)&As[r1_][c1] = a1;
        *(uint4*)&Bs[tid >> 2][(tid & 3)*8] = b0;
        __syncthreads();
        short8 av0 = *(const short8*)&As[wv*32 + lm][quad*8];
        short8 av1 = *(const short8*)&As[wv*32 + 16 + lm][quad*8];
        #pragma unroll
        for (int ns=0; ns<4; ns++){
            short8 bv = *(const short8*)&Bs[ns*16 + lm][quad*8];
            acc[0][ns] = __builtin_amdgcn_mfma_f32_16x16x32_bf16(av0, bv, acc[0][ns], 0,0,0);
            acc[1][ns] = __builtin_amdgcn_mfma_f32_16x16x32_bf16(av1, bv, acc[1][ns], 0,0,0);
        }
    }
    #pragma unroll
    for (int ms=0; ms<2; ms++)
      #pragma unroll
      for (int ns=0; ns<4; ns++){
        int n = n0 + ns*16 + lm;
        #pragma unroll
        for (int i=0;i<4;i++){
            int row = m0 + wv*32 + ms*16 + quad*4 + i;
            float v = acc[ms][ns][i];
            if (row < BL_){
                if (n < 200){
                    XH[(size_t)row*KP + 200 + n] = f2b(lreluf(v + ldd(batom, n, f32)));
                } else if (n < 400){
                    P16[(size_t)row*D_ + (n-200)] = f2b(v + ldd(bnei, n-200, f32));
                }
            } else if (n >= 200 && n < 400){
                Q16[(size_t)(row-BL_)*D_ + (n-200)] = f2b(v);
            }
        }
      }
}

// attention (all rounds): softmax + weighted neighbor sum -> bf16 wnei (stride KC, zero pad).
// XCD-locality swizzle: mol = bid&127. r0: compile-time-unrolled n (no div, no
// runtime-indexed idxn), fused Wab dot into the s_nei fill, interleaved shfl reductions.
__global__ void __launch_bounds__(256) k_attn(
        const unsigned short* __restrict__ cur16, const unsigned short* __restrict__ XH,
        const float* __restrict__ s1, const float* __restrict__ tb,
        const int* __restrict__ adl, const int* __restrict__ bdl,
        const unsigned short* __restrict__ P16, const unsigned short* __restrict__ Q16,
        const float* __restrict__ W_align, const float* __restrict__ b_align, int r,
        unsigned short* __restrict__ wnei, float* __restrict__ wsum){
    int bid = blockIdx.x;
    int mol = bid & (B_-1), chunk = bid >> 7;
    int wv = threadIdx.x >> 6, lane = threadIdx.x & 63;
    int al = mol*L_ + chunk*4 + wv;
    __shared__ float s_nei[4][N_][D_];

    int idxn[N_]; bool pad[N_];
    #pragma unroll
    for (int n=0;n<N_;n++){ idxn[n] = adl[al*N_ + n]; pad[n] = (idxn[n] == L_-1); }

    float s2[N_];
    float s1v;
    if (r == 0){
        const float* Wab = W_align + D_;
        float acc[N_+1];
        #pragma unroll
        for (int n=0;n<N_+1;n++) acc[n] = 0.f;
        #pragma unroll
        for (int n=0;n<N_;n++){
            int bd = bdl[al*N_ + n];
            const unsigned short* Prow = P16 + ((size_t)mol*L_ + idxn[n])*D_;
            const unsigned short* Qrow = Q16 + ((size_t)mol*MB_ + bd)*D_;
            for (int d=lane; d<D_; d+=64){
                float v = lreluf(bu2f(Prow[d]) + bu2f(Qrow[d]));
                s_nei[wv][n][d] = v;
                acc[n] += v * Wab[d];
            }
        }
        for (int d=lane; d<D_; d+=64)
            acc[N_] += bu2f(XH[(size_t)al*KP + 200 + d]) * W_align[d];
        #pragma unroll
        for (int o=32;o>0;o>>=1)
            #pragma unroll
            for (int n=0;n<N_+1;n++) acc[n] += __shfl_xor(acc[n],o);
        #pragma unroll
        for (int n=0;n<N_;n++) s2[n] = acc[n];
        s1v = acc[N_];
    } else {
        float tmp = 0.f;
        if (lane < N_) tmp = tb[mol*L_ + idxn[lane]];
        #pragma unroll
        for (int n=0;n<N_;n++) s2[n] = __shfl(tmp, n);
        s1v = s1[al];
    }

    float bav = b_align[r];
    float a[N_]; float mx = -1e30f;
    #pragma unroll
    for (int n=0;n<N_;n++){
        float v = lreluf(s1v + s2[n] + bav);
        if (pad[n]) v += NEGV;
        a[n] = v; mx = fmaxf(mx, v);
    }
    float w[N_]; float se = 0.f;
    #pragma unroll
    for (int n=0;n<N_;n++){ float e = expf(a[n]-mx); w[n]=e; se += e; }
    float inv = 1.f/se; float wsv = 0.f;
    #pragma unroll
    for (int n=0;n<N_;n++){ w[n] = pad[n] ? 0.f : w[n]*inv; wsv += w[n]; }

    if (r == 0){
        for (int d=lane; d<D_; d+=64){
            float acc = 0.f;
            #pragma unroll
            for (int n=0;n<N_;n++) acc += w[n] * s_nei[wv][n][d];
            wnei[(size_t)al*KC + d] = f2b(acc);
        }
    } else {
        for (int d=lane; d<D_; d+=64){
            float acc = 0.f;
            #pragma unroll
            for (int n=0;n<N_;n++) acc += w[n] * bu2f(cur16[((size_t)mol*L_ + idxn[n])*KC + d]);
            wnei[(size_t)al*KC + d] = f2b(acc);
        }
    }
    if (lane < 24) wnei[(size_t)al*KC + 200 + lane] = 0;
    if (lane==0) wsum[al] = wsv;
}

// MFMA ctx GEMM: elu(wnei[16384,KC] @ WatT[r]^T + wsum*bias) -> XH x-half.
// 64x64 tiles (R12-validated TLP mechanism): grid 256 m-tiles x 4 n = 1024 blocks.
__global__ void __launch_bounds__(256) k_ctxmfma(const unsigned short* __restrict__ Wn,
        const float* __restrict__ wsum, const unsigned short* __restrict__ WatT,
        const float* __restrict__ bias, int r, unsigned short* __restrict__ XH){
    __shared__ unsigned short As[64][40];
    __shared__ unsigned short Bs[64][40];
    int tid = threadIdx.x;
    int m0 = ((int)blockIdx.x & 255) * 64;
    int n0 = ((int)blockIdx.x >> 8) * 64;
    const unsigned short* Bt = WatT + (size_t)r*NC*KC;
    int lane = tid & 63, wv = tid >> 6;
    int quad = lane >> 4, lm = lane & 15;
    f32x4 acc[4];
    #pragma unroll
    for (int b=0;b<4;b++) acc[b] = (f32x4){0.f,0.f,0.f,0.f};
    int r0_ = tid >> 2, c0 = (tid & 3) * 8;    // r0_ in [0,64)
    for (int ks = 0; ks < 7; ks++){
        uint4 a0 = *(const uint4*)&Wn[(size_t)(m0 + r0_)*KC + ks*32 + c0];
        uint4 b0 = *(const uint4*)&Bt[(size_t)(n0 + r0_)*KC + ks*32 + c0];
        __syncthreads();
        *(uint4*)&As[r0_][c0] = a0;
        *(uint4*)&Bs[r0_][c0] = b0;
        __syncthreads();
        short8 av = *(const short8*)&As[wv*16 + lm][quad*8];
        #pragma unroll
        for (int ns=0; ns<4; ns++){
            short8 bv = *(const short8*)&Bs[ns*16 + lm][quad*8];
            acc[ns] = __builtin_amdgcn_mfma_f32_16x16x32_bf16(av, bv, acc[ns], 0,0,0);
        }
    }
    #pragma unroll
    for (int ns=0; ns<4; ns++){
        int n = n0 + ns*16 + lm;
        if (n < 200){
            float bv = bias[r*D_ + n];
            #pragma unroll
            for (int i=0;i<4;i++){
                int row = m0 + wv*16 + quad*4 + i;
                float v = acc[ns][i] + wsum[row]*bv;
                XH[(size_t)row*KP + n] = f2b(eluf(v));
            }
        }
    }
}

// MFMA gate GEMM: C[16384,NP] = XH @ B2t[r]^T. 64x64 tiles (R12-validated TLP mechanism):
// grid 256 m-tiles x 13 n-tiles = 3328 blocks (~13/CU; LDS 10KB). C stride stays NP;
// cols 800-831 get garbage that k_gru2 never reads.
__global__ void __launch_bounds__(256) k_gemm(const unsigned short* __restrict__ XH,
        const unsigned short* __restrict__ B2t, unsigned short* __restrict__ C, int r){
    __shared__ unsigned short As[64][40];
    __shared__ unsigned short Bs[64][40];
    int tid = threadIdx.x;
    int m0 = ((int)blockIdx.x & 255) * 64;
    int n0 = ((int)blockIdx.x >> 8) * 64;
    const unsigned short* Bt = B2t + (size_t)r*NP*KP;
    int lane = tid & 63, wv = tid >> 6;
    int quad = lane >> 4, lm = lane & 15;
    f32x4 acc[4];
    #pragma unroll
    for (int b=0;b<4;b++) acc[b] = (f32x4){0.f,0.f,0.f,0.f};
    int r0_ = tid >> 2, c0 = (tid & 3) * 8;    // r0_ in [0,64)
    for (int ks = 0; ks < 13; ks++){
        uint4 a0 = *(const uint4*)&XH[(size_t)(m0 + r0_)*KP + ks*32 + c0];
        uint4 b0 = *(const uint4*)&Bt[(size_t)(n0 + r0_)*KP + ks*32 + c0];
        __syncthreads();
        *(uint4*)&As[r0_][c0] = a0;
        *(uint4*)&Bs[r0_][c0] = b0;
        __syncthreads();
        short8 av = *(const short8*)&As[wv*16 + lm][quad*8];
        #pragma unroll
        for (int ns=0; ns<4; ns++){
            short8 bv = *(const short8*)&Bs[ns*16 + lm][quad*8];
            acc[ns] = __builtin_amdgcn_mfma_f32_16x16x32_bf16(av, bv, acc[ns], 0,0,0);
        }
    }
    #pragma unroll
    for (int ns=0; ns<4; ns++)
        #pragma unroll
        for (int i=0;i<4;i++){
            int row = m0 + wv*16 + quad*4 + i;
            C[(size_t)row*NP + n0 + ns*16 + lm] = f2b(acc[ns][i]);
        }
}

// GRU combine, wave-per-atom; GRU state lives in XH h-half (bf16). Writes cur16;
// fuses next-round s1/tb dots (r<2) or curdot (r==2).
__global__ void __launch_bounds__(256) k_gru2(const unsigned short* __restrict__ C,
        unsigned short* __restrict__ XH, unsigned short* __restrict__ cur16,
        const float* __restrict__ bih, const float* __restrict__ bhh,
        const float* __restrict__ W_align, const float* __restrict__ Wma, int r,
        float* __restrict__ s1, float* __restrict__ tb, float* __restrict__ curdot){
    int wv = threadIdx.x >> 6, lane = threadIdx.x & 63;
    int al = blockIdx.x*4 + wv;
    size_t base = (size_t)al*NP;
    const float* bi = bih + r*G3D_;
    const float* bh = bhh + r*G3D_;
    const float* Wa = W_align + (r+1)*2*D_;   // dereferenced only when r<2
    bool last = (r == R_-1);
    float a1 = 0.f, a2 = 0.f;
    for (int j = lane; j < D_; j += 64){
        float rsum = bu2f(C[base + j]);
        float zsum = bu2f(C[base + 200 + j]);
        float gin  = bu2f(C[base + 400 + j]);
        float ghn  = bu2f(C[base + 600 + j]);
        float rr = sigmf(rsum + bi[j] + bh[j]);
        float zz = sigmf(zsum + bi[D_+j] + bh[D_+j]);
        float nn = tanhf(gin + bi[2*D_+j] + rr*(ghn + bh[2*D_+j]));
        size_t hx = (size_t)al*KP + 200 + j;
        float hv = bu2f(XH[hx]);
        float hn = (1.f-zz)*nn + zz*hv;
        XH[hx] = f2b(hn);
        float cv = fmaxf(hn, 0.f);
        cur16[(size_t)al*KC + j] = f2b(cv);
        if (last){
            a1 += cv * Wma[D_+j];
        } else {
            a1 += cv * Wa[j];
            a2 += cv * Wa[D_+j];
        }
    }
    if (lane < 24) cur16[(size_t)al*KC + 200 + lane] = 0;
    for (int o=32;o>0;o>>=1){ a1 += __shfl_xor(a1,o); a2 += __shfl_xor(a2,o); }
    if (lane==0){
        if (last) curdot[al] = a1;
        else { s1[al] = a1; tb[al] = a2; }
    }
}

__device__ __forceinline__ float brSum(float v, float* s_red){
    for (int o=32;o>0;o>>=1) v += __shfl_xor(v,o);
    int lane = threadIdx.x & 63, wid = threadIdx.x >> 6;
    __syncthreads();
    if (lane==0) s_red[wid] = v;
    __syncthreads();
    float r = 0.f;
    int nw = blockDim.x >> 6;
    for (int i=0;i<nw;i++) r += s_red[i];
    return r;
}

// 200-elem dot of a bf16 row (25x uint4) with an LDS f32 vector (16B-aligned)
__device__ __forceinline__ float dot200(const unsigned short* __restrict__ wrow,
                                        const float* __restrict__ v){
    const uint4* wp = (const uint4*)wrow;
    float a0=0.f, a1=0.f;
    #pragma unroll
    for (int kk=0; kk<25; kk++){
        uint4 u = wp[kk];
        f32x4 A = *(const f32x4*)&v[8*kk];
        f32x4 Bv = *(const f32x4*)&v[8*kk+4];
        a0 += A[0]*lo2f(u.x) + A[1]*hi2f(u.x);
        a1 += A[2]*lo2f(u.y) + A[3]*hi2f(u.y);
        a0 += Bv[0]*lo2f(u.z) + Bv[1]*hi2f(u.z);
        a1 += Bv[2]*lo2f(u.w) + Bv[3]*hi2f(u.w);
    }
    return a0 + a1;
}

// molecule phase, 512 threads (8 waves), phase-minimized (4 barriers/t-iter).
// Waves 0-3: full softmax redundantly in-register + wc; waves 4-7: gh GEMV concurrently.
// __launch_bounds__(512,1): only 128 blocks exist (1/CU), so do NOT let the compiler
// cap VGPR at 128 for a useless 2-blocks/CU target (R6: cap -> 1MB spill -> 73us).
// sched_barrier(0) after each GEMV row pins the live set (no cross-row load hoisting).
__global__ void __launch_bounds__(512, 1) k_mol(const unsigned short* __restrict__ cur16,
    const float* __restrict__ curdot, const float* __restrict__ atom_mask,
    const float* __restrict__ Wma, const float* __restrict__ bma,
    const unsigned short* __restrict__ WmtT, const float* __restrict__ bmt,
    const unsigned short* __restrict__ WGi, const unsigned short* __restrict__ WGh,
    const float* __restrict__ mbih, const float* __restrict__ mbhh,
    const unsigned short* __restrict__ WmeT, const float* __restrict__ bme,
    const float* __restrict__ Wout, const float* __restrict__ bout,
    void* __restrict__ out, const unsigned* __restrict__ amtag){
    int b = blockIdx.x, tid = threadIdx.x;
    int wv = tid >> 6, lane = tid & 63;
    int dq = tid & 255, cq = tid >> 8;
    __shared__ unsigned short s_cur[L_*KC];
    __shared__ float s_am[L_], s_neg[L_], s_cd[L_];
    __shared__ float s_wp[4][L_];      // per-wave private softmax weights
    __shared__ __attribute__((aligned(16))) float s_mf[D_];
    __shared__ __attribute__((aligned(16))) float s_act[D_];
    __shared__ __attribute__((aligned(16))) float s_wc[D_];
    __shared__ __attribute__((aligned(16))) float s_ctx[D_];
    __shared__ __attribute__((aligned(16))) float s_mf2[2*D_];
    __shared__ float s_gi[G3D_], s_gh[G3D_];
    __shared__ float s_wma[D_], s_bmt[D_], s_bi[G3D_], s_bh[G3D_];
    __shared__ float s_part[2][256];
    __shared__ float s_red[8];
    __shared__ float s_wsm;
    const uint4* src = (const uint4*)(cur16 + (size_t)b*L_*KC);
    for (int i = tid; i < L_*KC/8; i += 512) ((uint4*)s_cur)[i] = src[i];
    if (tid < L_){
        float am = atom_mask[b*L_ + tid];
        s_am[tid] = am;
        s_neg[tid] = (am == 0.f) ? NEGV : 0.f;
        s_cd[tid] = curdot[b*L_ + tid];
    }
    if (tid < D_){ s_wma[tid] = Wma[tid]; s_bmt[tid] = bmt[tid]; }
    for (int j = tid; j < G3D_; j += 512){
        s_bi[j] = mbih[j];
        s_bh[j] = mbhh[j];
    }
    __syncthreads();
    {   // mol_feature = sum_l am[l]*cur[l,:]
        float a0 = 0.f, a1 = 0.f;
        if (dq < D_)
            for (int l=cq*64; l<cq*64+64; l+=2){
                a0 += bu2f(s_cur[l*KC + dq]) * s_am[l];
                a1 += bu2f(s_cur[(l+1)*KC + dq]) * s_am[l+1];
            }
        s_part[cq][dq] = a0 + a1;
        __syncthreads();
        if (tid < D_){
            float v = s_part[0][tid] + s_part[1][tid];
            s_mf[tid] = v; s_act[tid] = fmaxf(v, 0.f);
        }
        __syncthreads();
    }
    float bma0 = bma[0];
    #pragma unroll 1
    for (int t=0;t<T_;t++){
        if (wv < 4){
            // ---- redundant in-wave softmax (no block reductions) ----
            float a = s_act[lane]*s_wma[lane] + s_act[lane+64]*s_wma[lane+64];
            a += s_act[lane+128]*s_wma[lane+128];
            if (lane < 8) a += s_act[lane+192]*s_wma[lane+192];
            #pragma unroll
            for (int o=32;o>0;o>>=1) a += __shfl_xor(a,o);       // s1v
            float sc0 = lreluf(a + s_cd[lane] + bma0) + s_neg[lane];
            float sc1 = lreluf(a + s_cd[lane+64] + bma0) + s_neg[lane+64];
            float m = fmaxf(sc0, sc1);
            #pragma unroll
            for (int o=32;o>0;o>>=1) m = fmaxf(m, __shfl_xor(m,o));
            float e0 = expf(sc0 - m), e1 = expf(sc1 - m);
            float s = e0 + e1;
            #pragma unroll
            for (int o=32;o>0;o>>=1) s += __shfl_xor(s,o);
            float inv = 1.f/s;
            float w0 = e0*inv*s_am[lane], w1 = e1*inv*s_am[lane+64];
            float ws = w0 + w1;
            #pragma unroll
            for (int o=32;o>0;o>>=1) ws += __shfl_xor(ws,o);
            s_wp[wv][lane] = w0; s_wp[wv][lane+64] = w1;
            if (tid == 0) s_wsm = ws;
            // ---- wc[d] = sum_l w[l]*cur[l][d]  (d = tid, own wave's w copy) ----
            if (tid < D_){
                float acc = 0.f;
                #pragma unroll 16
                for (int l=0; l<L_; l++)
                    acc += s_wp[wv][l] * bu2f(s_cur[l*KC + tid]);
                s_wc[tid] = acc;
            }
        } else {
            // ---- gh GEMV (depends only on s_mf): 600 rows over 256 threads ----
            int h = tid - 256;
            #pragma unroll 1
            for (int rr=0; rr<3; rr++){
                int row = h + rr*256;
                if (row < G3D_)
                    s_gh[row] = dot200(WGh + (size_t)row*D_, s_mf);
                __builtin_amdgcn_sched_barrier(0);   // pin live set per row
            }
        }
        __syncthreads();   // #1: s_wc, s_gh, s_wsm ready
        if (tid < D_){
            float acc = dot200(WmtT + (size_t)tid*D_, s_wc);
            s_ctx[tid] = eluf(acc + s_wsm * s_bmt[tid]);
        }
        __syncthreads();   // #2: s_ctx ready
        {
            #pragma unroll 1
            for (int rr=0; rr<2; rr++){
                int row = tid + rr*512;
                if (row < G3D_)
                    s_gi[row] = dot200(WGi + (size_t)row*D_, s_ctx);
                __builtin_amdgcn_sched_barrier(0);   // pin live set per row
            }
        }
        __syncthreads();   // #3: s_gi ready
        if (tid < D_){
            int d = tid;
            float rr = sigmf(s_gi[d] + s_bi[d] + s_gh[d] + s_bh[d]);
            float zz = sigmf(s_gi[D_+d] + s_bi[D_+d] + s_gh[D_+d] + s_bh[D_+d]);
            float nn = tanhf(s_gi[2*D_+d] + s_bi[2*D_+d] + rr*(s_gh[2*D_+d] + s_bh[2*D_+d]));
            float nm = (1.f-zz)*nn + zz*s_mf[d];
            s_mf[d] = nm; s_act[d] = fmaxf(nm, 0.f);
        }
        __syncthreads();   // #4: s_mf/s_act for next t (or epilogue)
        __builtin_amdgcn_sched_barrier(0);           // no cross-t pipelining
    }
    const float dd = (float)(R_ - 2);
    if (tid < 2*D_) s_mf2[tid] = (tid < D_) ? s_mf[tid] : s_mf[tid - D_] + dd;
    __syncthreads();
    float p2 = 0.f;
    if (tid < D_){
        const uint4* wp = (const uint4*)(WmeT + (size_t)tid*400);
        float a0=0.f, a1=0.f;
        #pragma unroll
        for (int kk=0; kk<50; kk++){
            uint4 u = wp[kk];
            f32x4 wA = *(const f32x4*)&s_mf2[8*kk];
            f32x4 wB = *(const f32x4*)&s_mf2[8*kk+4];
            a0 += wA[0]*lo2f(u.x) + wA[1]*hi2f(u.x);
            a1 += wA[2]*lo2f(u.y) + wA[3]*hi2f(u.y);
            a0 += wB[0]*lo2f(u.z) + wB[1]*hi2f(u.z);
            a1 += wB[2]*lo2f(u.w) + wB[3]*hi2f(u.w);
        }
        p2 = (a0 + a1 + bme[tid]) * Wout[tid];
    }
    float o = brSum(p2, s_red);
    if (tid==0){
        o += bout[0];
        if (*amtag == FP32TAG) ((float*)out)[b] = o;
        else ((bf16*)out)[b] = __float2bfloat16(o);
    }
}

extern "C" void kernel_launch(void* const* d_in, const int* in_sizes, int n_in,
                              void* d_out, int out_size, void* d_ws, size_t ws_size,
                              hipStream_t stream) {
    const int* adl = (const int*)d_in[2];
    const int* bdl = (const int*)d_in[3];
    const unsigned* amtag = (const unsigned*)d_in[4];

    static const int srcidx[NSEG] = {4,9,10,12,15,16,17,18,20,23,24,26,27,28};
    static const int segsz[NSEG]  = {16384,1200,3,600,1800,1800,400,1,200,600,600,200,200,1};
    CvtArgs ca;
    int ofs[NSEG+1]; ofs[0] = 0;
    for (int i=0;i<NSEG;i++){ ca.src[i] = d_in[srcidx[i]]; ca.ofs[i] = ofs[i]; ofs[i+1] = ofs[i] + segsz[i]; }
    ca.ofs[NSEG] = ofs[NSEG];   // 23989

    // ws layout. ~54 MB total.
    float* ws   = (float*)d_ws;
    float* conv = ws;                                            // 24000 fl
    unsigned short* XH    = (unsigned short*)(conv + 24000);     // BL_*KP sh
    unsigned short* B2t   = XH + (size_t)BL_*KP;                 // PREPB_N sh
    unsigned short* WatT  = B2t + PREPB_N;                       // PREPW_N sh
    unsigned short* WGi   = WatT + PREPW_N;                      // PREPM_N sh
    unsigned short* WGh   = WGi + PREPM_N;                       // PREPM_N sh
    unsigned short* WmtT  = WGh + PREPM_N;                       // PREPT_N sh
    unsigned short* WmeT  = WmtT + PREPT_N;                      // PREPE_N sh
    unsigned short* Bi16  = WmeT + PREPE_N;                      // BI_N sh
    unsigned short* cur16 = Bi16 + BI_N;                         // BL_*KC sh
    unsigned short* creg  = cur16 + (size_t)BL_*KC;              // C region: BL_*NP sh
    unsigned short* C = creg;
    unsigned short* A16  = creg;                                 // overlay (dead before wnei)
    unsigned short* wnei = creg;                                 // BL_*KC sh overlay
    unsigned short* Q16  = creg + (size_t)BL_*KC;                // B_*MB_*D_ sh overlay
    unsigned short* P16  = Q16 + (size_t)B_*MB_*D_;              // BL_*D_ sh overlay
    float* s1     = (float*)(creg + (size_t)BL_*NP);
    float* tb     = s1 + BL_;
    float* wsum   = tb + BL_;
    float* curdot = wsum + BL_;

    const float* c_amask = conv + ofs[0];
    const float* c_Walign= conv + ofs[1];
    const float* c_balign= conv + ofs[2];
    const float* c_batt  = conv + ofs[3];
    const float* c_bih   = conv + ofs[4];
    const float* c_bhh   = conv + ofs[5];
    const float* c_Wma   = conv + ofs[6];
    const float* c_bma   = conv + ofs[7];
    const float* c_bmt   = conv + ofs[8];
    const float* c_mbih  = conv + ofs[9];
    const float* c_mbhh  = conv + ofs[10];
    const float* c_bme   = conv + ofs[11];
    const float* c_Wout  = conv + ofs[12];
    const float* c_bout  = conv + ofs[13];

    PrepArgs A;
    A.cvt = ca;
    A.Wih = d_in[13]; A.Whh = d_in[14]; A.Watt = d_in[11];
    A.mWih = d_in[21]; A.mWhh = d_in[22]; A.Wmt = d_in[19]; A.Wme = d_in[25];
    A.bond = d_in[1]; A.Wnei = d_in[7]; A.atom = d_in[0]; A.Watom = d_in[5];
    A.conv = conv;
    A.B2t = B2t; A.WatT = WatT; A.WGi = WGi; A.WGh = WGh; A.WmtT = WmtT; A.WmeT = WmeT;
    A.XH = XH; A.A16 = A16; A.Bi16 = Bi16;
    A.amtag = amtag;
    A.ew_total = CONV_N + PREPB_N + PREPW_N + PREPG_N + PREPT_N + PREPE_N
               + XHPAD_N + A_N + BI_N;   // 5110773

    k_prep<<<(A.ew_total + 255)/256, 256, 0, stream>>>(A);
    k_initmm<<<(AROWS/128)*7, 256, 0, stream>>>(A16, Bi16, d_in[6], d_in[8],
                                                XH, P16, Q16, amtag);

    for (int r=0; r<R_; r++){
        k_attn<<<BL_/4, 256, 0, stream>>>(cur16, XH, s1, tb, adl, bdl, P16, Q16,
                                          c_Walign, c_balign, r, wnei, wsum);
        k_ctxmfma<<<(BL_/64)*(NC/64), 256, 0, stream>>>(wnei, wsum, WatT, c_batt, r, XH);
        k_gemm<<<(BL_/64)*NT2, 256, 0, stream>>>(XH, B2t, C, r);
        k_gru2<<<BL_/4, 256, 0, stream>>>(C, XH, cur16, c_bih, c_bhh,
                                          c_Walign, c_Wma, r, s1, tb, curdot);
    }

    k_mol<<<B_, 512, 0, stream>>>(cur16, curdot, c_amask, c_Wma, c_bma, WmtT, c_bmt,
                                  WGi, WGh, c_mbih, c_mbhh, WmeT, c_bme, c_Wout, c_bout,
                                  d_out, amtag);
}

// Round 14
// 397.664 us; speedup vs baseline: 1.2925x; 1.0035x over previous
//
#include <hip/hip_runtime.h>
#include <hip/hip_bf16.h>
#include <math.h>
#include <string.h>

#define B_ 128
#define L_ 128
#define N_ 6
#define FA_ 39
#define FB_ 10
#define D_ 200
#define MB_ 256
#define R_ 3
#define T_ 2
#define NEGV -9e8f
#define BL_ (B_*L_)        // 16384
#define G3D_ (3*D_)        // 600
#define FP32TAG 0x3F800000u
#define KP 416             // padded K for gate GEMM
#define NP 896             // padded N for gate GEMM (C stride; cols 800+ dead)
#define NT2 13             // k_gemm n-tiles of 64 (13*64=832 >= 800 live cols)
#define KC 224             // padded K for ctx GEMM (7*32)
#define NC 256             // padded N for ctx GEMM

typedef __hip_bfloat16 bf16;
typedef __attribute__((ext_vector_type(8))) short short8;
typedef __attribute__((ext_vector_type(4))) float f32x4;

__device__ __forceinline__ float b2f(const bf16 x){ return __bfloat162float(x); }
__device__ __forceinline__ unsigned short f2b(float v){ bf16 t = __float2bfloat16(v); return *reinterpret_cast<unsigned short*>(&t); }
__device__ __forceinline__ float bu2f(unsigned short u){ unsigned x = ((unsigned)u)<<16; float f; memcpy(&f,&x,4); return f; }
__device__ __forceinline__ float lo2f(unsigned x){ unsigned y = x<<16; float f; memcpy(&f,&y,4); return f; }
__device__ __forceinline__ float hi2f(unsigned x){ unsigned y = x & 0xffff0000u; float f; memcpy(&f,&y,4); return f; }
__device__ __forceinline__ float lreluf(float x){ return x>=0.f ? x : 0.01f*x; }
__device__ __forceinline__ float eluf(float x){ return x>0.f ? x : expm1f(x); }
__device__ __forceinline__ float sigmf(float x){ return 1.f/(1.f+expf(-x)); }

#define NSEG 14
struct CvtArgs { const void* src[NSEG]; int ofs[NSEG+1]; };

#define PREPB_N (R_*NP*KP)     // 1118208
#define PREPW_N (R_*NC*KC)     // 172032
#define PREPM_N (D_*G3D_)      // 120000 (per matrix)
#define PREPG_N (2*PREPM_N)    // 240000 (WGi + WGh flat bf16)
#define PREPT_N 40000          // WmtT [d][k]
#define PREPE_N 80000          // WmeT [d][k0..399]
#define CONV_N 23989
#define XHPAD_N (BL_*16)       // 262144
#define AROWS (BL_ + B_*MB_)   // 49152
#define A_N (AROWS*64)         // 3145728
#define BI_N (448*64)          // 28672

struct PrepArgs {
    CvtArgs cvt;
    const void *Wih, *Whh, *Watt, *mWih, *mWhh, *Wmt, *Wme;
    const void *bond, *Wnei, *atom, *Watom;
    float* conv;
    unsigned short *B2t, *WatT, *WGi, *WGh, *WmtT, *WmeT, *XH, *A16, *Bi16;
    const unsigned* amtag;
    int ew_total;
};

__device__ __forceinline__ float ldd(const void* p, size_t i, bool f32){
    return f32 ? ((const float*)p)[i] : b2f(((const bf16*)p)[i]);
}

// prologue elementwise: small-param convert + all weight repacks + XH pad + A16/Bi16 packing
__global__ void __launch_bounds__(256) k_prep(PrepArgs A){
    bool f32 = (*A.amtag == FP32TAG);
    int i = blockIdx.x*256 + (int)threadIdx.x;
    if (i >= A.ew_total) return;
    if (i < CONV_N){
        int s = 0;
        while (i >= A.cvt.ofs[s+1]) s++;
        A.conv[i] = ldd(A.cvt.src[s], i - A.cvt.ofs[s], f32);
        return;
    }
    int i2 = i - CONV_N;
    if (i2 < PREPB_N){
        int kk = i2 % KP;
        int rest = i2 / KP;
        int n = rest % NP;
        int r = rest / NP;
        float v = 0.f;
        if (kk < 200){
            if (n < 600) v = ldd(A.Wih, ((size_t)(r*G3D_ + n))*D_ + kk, f32);
        } else if (kk < 400){
            int j = -1;
            if (n < 400) j = n;
            else if (n >= 600 && n < 800) j = n - 200;
            if (j >= 0) v = ldd(A.Whh, ((size_t)(r*G3D_ + j))*D_ + (kk-200), f32);
        }
        A.B2t[i2] = f2b(v);
        return;
    }
    int i3 = i2 - PREPB_N;
    if (i3 < PREPW_N){
        int kk = i3 % KC;
        int rest = i3 / KC;
        int n = rest % NC;
        int r = rest / NC;
        float v = 0.f;
        if (kk < 200 && n < 200) v = ldd(A.Watt, ((size_t)r*D_ + kk)*D_ + n, f32);
        A.WatT[i3] = f2b(v);
        return;
    }
    int i4 = i3 - PREPW_N;
    if (i4 < PREPG_N){
        // WGi = mWih rows (row-per-output already), WGh = mWhh rows; flat bf16 convert
        int half = i4 / PREPM_N;
        int s = i4 - half*PREPM_N;
        (half ? A.WGh : A.WGi)[s] = f2b(ldd(half ? A.mWhh : A.mWih, s, f32));
        return;
    }
    int i5 = i4 - PREPG_N;
    if (i5 < PREPT_N){
        // WmtT[d*200+k] = Wmt[k*200+d]; source-ordered reads
        int k = i5 / 200, d = i5 % 200;
        A.WmtT[(size_t)d*200 + k] = f2b(ldd(A.Wmt, i5, f32));
        return;
    }
    int i6 = i5 - PREPT_N;
    if (i6 < PREPE_N){
        // WmeT[d*400+k] = Wme[k*200+d], k<400; source-ordered reads
        int k = i6 / 200, d = i6 % 200;
        A.WmeT[(size_t)d*400 + k] = f2b(ldd(A.Wme, i6, f32));
        return;
    }
    int i7 = i6 - PREPE_N;
    if (i7 < XHPAD_N){
        int al = i7 >> 4, j = i7 & 15;
        A.XH[(size_t)al*KP + 400 + j] = 0;
        return;
    }
    int i8 = i7 - XHPAD_N;
    if (i8 < A_N){
        int row = i8 >> 6, k = i8 & 63;
        float v = 0.f;
        if (row < BL_){
            if (k < FA_) v = ldd(A.atom, (size_t)row*FA_ + k, f32);
        } else {
            int rb = row - BL_;
            if (k >= FA_ && k < FA_+FB_) v = ldd(A.bond, (size_t)rb*FB_ + (k-FA_), f32);
        }
        A.A16[i8] = f2b(v);
        return;
    }
    int i9 = i8 - A_N;
    if (i9 < BI_N){
        int n = i9 >> 6, k = i9 & 63;
        float v = 0.f;
        if (n < 200){
            if (k < FA_) v = ldd(A.Watom, (size_t)k*D_ + n, f32);
        } else if (n < 400){
            if (k < FA_+FB_) v = ldd(A.Wnei, (size_t)k*D_ + (n-200), f32);
        }
        A.Bi16[i9] = f2b(v);
    }
}

// MFMA init GEMM: C[49152,448] = A16 @ Bi16^T. Atom rows -> XH h-half (lrelu+b_atom) and
// P16 (+b_nei); bond rows -> Q16. 128x64 tile, K=64 (2 steps).
__global__ void __launch_bounds__(256) k_initmm(const unsigned short* __restrict__ A16,
        const unsigned short* __restrict__ Bi16,
        const void* __restrict__ batom, const void* __restrict__ bnei,
        unsigned short* __restrict__ XH, unsigned short* __restrict__ P16,
        unsigned short* __restrict__ Q16, const unsigned* __restrict__ amtag){
    __shared__ unsigned short As[128][40];
    __shared__ unsigned short Bs[64][40];
    bool f32 = (*amtag == FP32TAG);
    int tid = threadIdx.x;
    int mt = (int)blockIdx.x / 7, nt = (int)blockIdx.x % 7;
    int m0 = mt*128, n0 = nt*64;
    if (m0 >= BL_ && n0 + 64 <= 200) return;   // bond rows x atom-feature cols: all dead
    int lane = tid & 63, wv = tid >> 6;
    int quad = lane >> 4, lm = lane & 15;
    f32x4 acc[2][4];
    #pragma unroll
    for (int a=0;a<2;a++)
        #pragma unroll
        for (int b=0;b<4;b++) acc[a][b] = (f32x4){0.f,0.f,0.f,0.f};
    for (int ks = 0; ks < 2; ks++){
        int r0_ = tid >> 2, c0 = (tid & 3) * 8;
        int r1_ = (tid + 256) >> 2, c1 = ((tid + 256) & 3) * 8;
        uint4 a0 = *(const uint4*)&A16[(size_t)(m0 + r0_)*64 + ks*32 + c0];
        uint4 a1 = *(const uint4*)&A16[(size_t)(m0 + r1_)*64 + ks*32 + c1];
        uint4 b0 = *(const uint4*)&Bi16[(size_t)(n0 + (tid >> 2))*64 + ks*32 + (tid & 3)*8];
        __syncthreads();
        *(uint4*)&As[r0_][c0] = a0;
        *(uint4*)&As[r1_][c1] = a1;
        *(uint4*)&Bs[tid >> 2][(tid & 3)*8] = b0;
        __syncthreads();
        short8 av0 = *(const short8*)&As[wv*32 + lm][quad*8];
        short8 av1 = *(const short8*)&As[wv*32 + 16 + lm][quad*8];
        #pragma unroll
        for (int ns=0; ns<4; ns++){
            short8 bv = *(const short8*)&Bs[ns*16 + lm][quad*8];
            acc[0][ns] = __builtin_amdgcn_mfma_f32_16x16x32_bf16(av0, bv, acc[0][ns], 0,0,0);
            acc[1][ns] = __builtin_amdgcn_mfma_f32_16x16x32_bf16(av1, bv, acc[1][ns], 0,0,0);
        }
    }
    #pragma unroll
    for (int ms=0; ms<2; ms++)
      #pragma unroll
      for (int ns=0; ns<4; ns++){
        int n = n0 + ns*16 + lm;
        #pragma unroll
        for (int i=0;i<4;i++){
            int row = m0 + wv*32 + ms*16 + quad*4 + i;
            float v = acc[ms][ns][i];
            if (row < BL_){
                if (n < 200){
                    XH[(size_t)row*KP + 200 + n] = f2b(lreluf(v + ldd(batom, n, f32)));
                } else if (n < 400){
                    P16[(size_t)row*D_ + (n-200)] = f2b(v + ldd(bnei, n-200, f32));
                }
            } else if (n >= 200 && n < 400){
                Q16[(size_t)(row-BL_)*D_ + (n-200)] = f2b(v);
            }
        }
      }
}

// attention (all rounds): softmax + weighted neighbor sum -> bf16 wnei (stride KC, zero pad).
// XCD-locality swizzle: mol = bid&127. r0: compile-time-unrolled n (no div, no
// runtime-indexed idxn), fused Wab dot into the s_nei fill, interleaved shfl reductions.
__global__ void __launch_bounds__(256) k_attn(
        const unsigned short* __restrict__ cur16, const unsigned short* __restrict__ XH,
        const float* __restrict__ s1, const float* __restrict__ tb,
        const int* __restrict__ adl, const int* __restrict__ bdl,
        const unsigned short* __restrict__ P16, const unsigned short* __restrict__ Q16,
        const float* __restrict__ W_align, const float* __restrict__ b_align, int r,
        unsigned short* __restrict__ wnei, float* __restrict__ wsum){
    int bid = blockIdx.x;
    int mol = bid & (B_-1), chunk = bid >> 7;
    int wv = threadIdx.x >> 6, lane = threadIdx.x & 63;
    int al = mol*L_ + chunk*4 + wv;
    __shared__ float s_nei[4][N_][D_];

    int idxn[N_]; bool pad[N_];
    #pragma unroll
    for (int n=0;n<N_;n++){ idxn[n] = adl[al*N_ + n]; pad[n] = (idxn[n] == L_-1); }

    float s2[N_];
    float s1v;
    if (r == 0){
        const float* Wab = W_align + D_;
        float acc[N_+1];
        #pragma unroll
        for (int n=0;n<N_+1;n++) acc[n] = 0.f;
        #pragma unroll
        for (int n=0;n<N_;n++){
            int bd = bdl[al*N_ + n];
            const unsigned short* Prow = P16 + ((size_t)mol*L_ + idxn[n])*D_;
            const unsigned short* Qrow = Q16 + ((size_t)mol*MB_ + bd)*D_;
            for (int d=lane; d<D_; d+=64){
                float v = lreluf(bu2f(Prow[d]) + bu2f(Qrow[d]));
                s_nei[wv][n][d] = v;
                acc[n] += v * Wab[d];
            }
        }
        for (int d=lane; d<D_; d+=64)
            acc[N_] += bu2f(XH[(size_t)al*KP + 200 + d]) * W_align[d];
        #pragma unroll
        for (int o=32;o>0;o>>=1)
            #pragma unroll
            for (int n=0;n<N_+1;n++) acc[n] += __shfl_xor(acc[n],o);
        #pragma unroll
        for (int n=0;n<N_;n++) s2[n] = acc[n];
        s1v = acc[N_];
    } else {
        float tmp = 0.f;
        if (lane < N_) tmp = tb[mol*L_ + idxn[lane]];
        #pragma unroll
        for (int n=0;n<N_;n++) s2[n] = __shfl(tmp, n);
        s1v = s1[al];
    }

    float bav = b_align[r];
    float a[N_]; float mx = -1e30f;
    #pragma unroll
    for (int n=0;n<N_;n++){
        float v = lreluf(s1v + s2[n] + bav);
        if (pad[n]) v += NEGV;
        a[n] = v; mx = fmaxf(mx, v);
    }
    float w[N_]; float se = 0.f;
    #pragma unroll
    for (int n=0;n<N_;n++){ float e = expf(a[n]-mx); w[n]=e; se += e; }
    float inv = 1.f/se; float wsv = 0.f;
    #pragma unroll
    for (int n=0;n<N_;n++){ w[n] = pad[n] ? 0.f : w[n]*inv; wsv += w[n]; }

    if (r == 0){
        for (int d=lane; d<D_; d+=64){
            float acc = 0.f;
            #pragma unroll
            for (int n=0;n<N_;n++) acc += w[n] * s_nei[wv][n][d];
            wnei[(size_t)al*KC + d] = f2b(acc);
        }
    } else {
        for (int d=lane; d<D_; d+=64){
            float acc = 0.f;
            #pragma unroll
            for (int n=0;n<N_;n++) acc += w[n] * bu2f(cur16[((size_t)mol*L_ + idxn[n])*KC + d]);
            wnei[(size_t)al*KC + d] = f2b(acc);
        }
    }
    if (lane < 24) wnei[(size_t)al*KC + 200 + lane] = 0;
    if (lane==0) wsum[al] = wsv;
}

// MFMA ctx GEMM: elu(wnei[16384,KC] @ WatT[r]^T + wsum*bias) -> XH x-half.
// 64x64 tiles (R12-validated TLP mechanism): grid 256 m-tiles x 4 n = 1024 blocks.
__global__ void __launch_bounds__(256) k_ctxmfma(const unsigned short* __restrict__ Wn,
        const float* __restrict__ wsum, const unsigned short* __restrict__ WatT,
        const float* __restrict__ bias, int r, unsigned short* __restrict__ XH){
    __shared__ unsigned short As[64][40];
    __shared__ unsigned short Bs[64][40];
    int tid = threadIdx.x;
    int m0 = ((int)blockIdx.x & 255) * 64;
    int n0 = ((int)blockIdx.x >> 8) * 64;
    const unsigned short* Bt = WatT + (size_t)r*NC*KC;
    int lane = tid & 63, wv = tid >> 6;
    int quad = lane >> 4, lm = lane & 15;
    f32x4 acc[4];
    #pragma unroll
    for (int b=0;b<4;b++) acc[b] = (f32x4){0.f,0.f,0.f,0.f};
    int r0_ = tid >> 2, c0 = (tid & 3) * 8;    // r0_ in [0,64)
    for (int ks = 0; ks < 7; ks++){
        uint4 a0 = *(const uint4*)&Wn[(size_t)(m0 + r0_)*KC + ks*32 + c0];
        uint4 b0 = *(const uint4*)&Bt[(size_t)(n0 + r0_)*KC + ks*32 + c0];
        __syncthreads();
        *(uint4*)&As[r0_][c0] = a0;
        *(uint4*)&Bs[r0_][c0] = b0;
        __syncthreads();
        short8 av = *(const short8*)&As[wv*16 + lm][quad*8];
        #pragma unroll
        for (int ns=0; ns<4; ns++){
            short8 bv = *(const short8*)&Bs[ns*16 + lm][quad*8];
            acc[ns] = __builtin_amdgcn_mfma_f32_16x16x32_bf16(av, bv, acc[ns], 0,0,0);
        }
    }
    #pragma unroll
    for (int ns=0; ns<4; ns++){
        int n = n0 + ns*16 + lm;
        if (n < 200){
            float bv = bias[r*D_ + n];
            #pragma unroll
            for (int i=0;i<4;i++){
                int row = m0 + wv*16 + quad*4 + i;
                float v = acc[ns][i] + wsum[row]*bv;
                XH[(size_t)row*KP + n] = f2b(eluf(v));
            }
        }
    }
}

// MFMA gate GEMM: C[16384,NP] = XH @ B2t[r]^T. 64x64 tiles (R12-validated TLP mechanism):
// grid 256 m-tiles x 13 n-tiles = 3328 blocks (~13/CU; LDS 10KB). C stride stays NP;
// cols 800-831 get garbage that k_gru2 never reads.
__global__ void __launch_bounds__(256) k_gemm(const unsigned short* __restrict__ XH,
        const unsigned short* __restrict__ B2t, unsigned short* __restrict__ C, int r){
    __shared__ unsigned short As[64][40];
    __shared__ unsigned short Bs[64][40];
    int tid = threadIdx.x;
    int m0 = ((int)blockIdx.x & 255) * 64;
    int n0 = ((int)blockIdx.x >> 8) * 64;
    const unsigned short* Bt = B2t + (size_t)r*NP*KP;
    int lane = tid & 63, wv = tid >> 6;
    int quad = lane >> 4, lm = lane & 15;
    f32x4 acc[4];
    #pragma unroll
    for (int b=0;b<4;b++) acc[b] = (f32x4){0.f,0.f,0.f,0.f};
    int r0_ = tid >> 2, c0 = (tid & 3) * 8;    // r0_ in [0,64)
    for (int ks = 0; ks < 13; ks++){
        uint4 a0 = *(const uint4*)&XH[(size_t)(m0 + r0_)*KP + ks*32 + c0];
        uint4 b0 = *(const uint4*)&Bt[(size_t)(n0 + r0_)*KP + ks*32 + c0];
        __syncthreads();
        *(uint4*)&As[r0_][c0] = a0;
        *(uint4*)&Bs[r0_][c0] = b0;
        __syncthreads();
        short8 av = *(const short8*)&As[wv*16 + lm][quad*8];
        #pragma unroll
        for (int ns=0; ns<4; ns++){
            short8 bv = *(const short8*)&Bs[ns*16 + lm][quad*8];
            acc[ns] = __builtin_amdgcn_mfma_f32_16x16x32_bf16(av, bv, acc[ns], 0,0,0);
        }
    }
    #pragma unroll
    for (int ns=0; ns<4; ns++)
        #pragma unroll
        for (int i=0;i<4;i++){
            int row = m0 + wv*16 + quad*4 + i;
            C[(size_t)row*NP + n0 + ns*16 + lm] = f2b(acc[ns][i]);
        }
}

// GRU combine, wave-per-atom; GRU state lives in XH h-half (bf16). Writes cur16;
// fuses next-round s1/tb dots (r<2) or curdot (r==2).
__global__ void __launch_bounds__(256) k_gru2(const unsigned short* __restrict__ C,
        unsigned short* __restrict__ XH, unsigned short* __restrict__ cur16,
        const float* __restrict__ bih, const float* __restrict__ bhh,
        const float* __restrict__ W_align, const float* __restrict__ Wma, int r,
        float* __restrict__ s1, float* __restrict__ tb, float* __restrict__ curdot){
    int wv = threadIdx.x >> 6, lane = threadIdx.x & 63;
    int al = blockIdx.x*4 + wv;
    size_t base = (size_t)al*NP;
    const float* bi = bih + r*G3D_;
    const float* bh = bhh + r*G3D_;
    const float* Wa = W_align + (r+1)*2*D_;   // dereferenced only when r<2
    bool last = (r == R_-1);
    float a1 = 0.f, a2 = 0.f;
    for (int j = lane; j < D_; j += 64){
        float rsum = bu2f(C[base + j]);
        float zsum = bu2f(C[base + 200 + j]);
        float gin  = bu2f(C[base + 400 + j]);
        float ghn  = bu2f(C[base + 600 + j]);
        float rr = sigmf(rsum + bi[j] + bh[j]);
        float zz = sigmf(zsum + bi[D_+j] + bh[D_+j]);
        float nn = tanhf(gin + bi[2*D_+j] + rr*(ghn + bh[2*D_+j]));
        size_t hx = (size_t)al*KP + 200 + j;
        float hv = bu2f(XH[hx]);
        float hn = (1.f-zz)*nn + zz*hv;
        XH[hx] = f2b(hn);
        float cv = fmaxf(hn, 0.f);
        cur16[(size_t)al*KC + j] = f2b(cv);
        if (last){
            a1 += cv * Wma[D_+j];
        } else {
            a1 += cv * Wa[j];
            a2 += cv * Wa[D_+j];
        }
    }
    if (lane < 24) cur16[(size_t)al*KC + 200 + lane] = 0;
    for (int o=32;o>0;o>>=1){ a1 += __shfl_xor(a1,o); a2 += __shfl_xor(a2,o); }
    if (lane==0){
        if (last) curdot[al] = a1;
        else { s1[al] = a1; tb[al] = a2; }
    }
}

__device__ __forceinline__ float brSum(float v, float* s_red){
    for (int o=32;o>0;o>>=1) v += __shfl_xor(v,o);
    int lane = threadIdx.x & 63, wid = threadIdx.x >> 6;
    __syncthreads();
    if (lane==0) s_red[wid] = v;
    __syncthreads();
    float r = 0.f;
    int nw = blockDim.x >> 6;
    for (int i=0;i<nw;i++) r += s_red[i];
    return r;
}

// 200-elem dot of a bf16 row (25x uint4) with an LDS f32 vector (16B-aligned)
__device__ __forceinline__ float dot200(const unsigned short* __restrict__ wrow,
                                        const float* __restrict__ v){
    const uint4* wp = (const uint4*)wrow;
    float a0=0.f, a1=0.f;
    #pragma unroll
    for (int kk=0; kk<25; kk++){
        uint4 u = wp[kk];
        f32x4 A = *(const f32x4*)&v[8*kk];
        f32x4 Bv = *(const f32x4*)&v[8*kk+4];
        a0 += A[0]*lo2f(u.x) + A[1]*hi2f(u.x);
        a1 += A[2]*lo2f(u.y) + A[3]*hi2f(u.y);
        a0 += Bv[0]*lo2f(u.z) + Bv[1]*hi2f(u.z);
        a1 += Bv[2]*lo2f(u.w) + Bv[3]*hi2f(u.w);
    }
    return a0 + a1;
}

// molecule phase, 512 threads (8 waves), phase-minimized (4 barriers/t-iter).
// Waves 0-3: full softmax redundantly in-register + wc; waves 4-7: gh GEMV concurrently.
// __launch_bounds__(512,1): only 128 blocks exist (1/CU) -> allow full 256-VGPR budget.
// R14: sched_barrier REMOVED inside gh/gi row loops (unroll-1 kept) so the compiler can
// software-pipeline the next row's 25 uint4 loads under the current row's FMAs (~128
// VGPRs of headroom = 1 row of prefetch). Spill sentinel: WRITE_SIZE must stay ~4KB.
__global__ void __launch_bounds__(512, 1) k_mol(const unsigned short* __restrict__ cur16,
    const float* __restrict__ curdot, const float* __restrict__ atom_mask,
    const float* __restrict__ Wma, const float* __restrict__ bma,
    const unsigned short* __restrict__ WmtT, const float* __restrict__ bmt,
    const unsigned short* __restrict__ WGi, const unsigned short* __restrict__ WGh,
    const float* __restrict__ mbih, const float* __restrict__ mbhh,
    const unsigned short* __restrict__ WmeT, const float* __restrict__ bme,
    const float* __restrict__ Wout, const float* __restrict__ bout,
    void* __restrict__ out, const unsigned* __restrict__ amtag){
    int b = blockIdx.x, tid = threadIdx.x;
    int wv = tid >> 6, lane = tid & 63;
    int dq = tid & 255, cq = tid >> 8;
    __shared__ unsigned short s_cur[L_*KC];
    __shared__ float s_am[L_], s_neg[L_], s_cd[L_];
    __shared__ float s_wp[4][L_];      // per-wave private softmax weights
    __shared__ __attribute__((aligned(16))) float s_mf[D_];
    __shared__ __attribute__((aligned(16))) float s_act[D_];
    __shared__ __attribute__((aligned(16))) float s_wc[D_];
    __shared__ __attribute__((aligned(16))) float s_ctx[D_];
    __shared__ __attribute__((aligned(16))) float s_mf2[2*D_];
    __shared__ float s_gi[G3D_], s_gh[G3D_];
    __shared__ float s_wma[D_], s_bmt[D_], s_bi[G3D_], s_bh[G3D_];
    __shared__ float s_part[2][256];
    __shared__ float s_red[8];
    __shared__ float s_wsm;
    const uint4* src = (const uint4*)(cur16 + (size_t)b*L_*KC);
    for (int i = tid; i < L_*KC/8; i += 512) ((uint4*)s_cur)[i] = src[i];
    if (tid < L_){
        float am = atom_mask[b*L_ + tid];
        s_am[tid] = am;
        s_neg[tid] = (am == 0.f) ? NEGV : 0.f;
        s_cd[tid] = curdot[b*L_ + tid];
    }
    if (tid < D_){ s_wma[tid] = Wma[tid]; s_bmt[tid] = bmt[tid]; }
    for (int j = tid; j < G3D_; j += 512){
        s_bi[j] = mbih[j];
        s_bh[j] = mbhh[j];
    }
    __syncthreads();
    {   // mol_feature = sum_l am[l]*cur[l,:]
        float a0 = 0.f, a1 = 0.f;
        if (dq < D_)
            for (int l=cq*64; l<cq*64+64; l+=2){
                a0 += bu2f(s_cur[l*KC + dq]) * s_am[l];
                a1 += bu2f(s_cur[(l+1)*KC + dq]) * s_am[l+1];
            }
        s_part[cq][dq] = a0 + a1;
        __syncthreads();
        if (tid < D_){
            float v = s_part[0][tid] + s_part[1][tid];
            s_mf[tid] = v; s_act[tid] = fmaxf(v, 0.f);
        }
        __syncthreads();
    }
    float bma0 = bma[0];
    #pragma unroll 1
    for (int t=0;t<T_;t++){
        if (wv < 4){
            // ---- redundant in-wave softmax (no block reductions) ----
            float a = s_act[lane]*s_wma[lane] + s_act[lane+64]*s_wma[lane+64];
            a += s_act[lane+128]*s_wma[lane+128];
            if (lane < 8) a += s_act[lane+192]*s_wma[lane+192];
            #pragma unroll
            for (int o=32;o>0;o>>=1) a += __shfl_xor(a,o);       // s1v
            float sc0 = lreluf(a + s_cd[lane] + bma0) + s_neg[lane];
            float sc1 = lreluf(a + s_cd[lane+64] + bma0) + s_neg[lane+64];
            float m = fmaxf(sc0, sc1);
            #pragma unroll
            for (int o=32;o>0;o>>=1) m = fmaxf(m, __shfl_xor(m,o));
            float e0 = expf(sc0 - m), e1 = expf(sc1 - m);
            float s = e0 + e1;
            #pragma unroll
            for (int o=32;o>0;o>>=1) s += __shfl_xor(s,o);
            float inv = 1.f/s;
            float w0 = e0*inv*s_am[lane], w1 = e1*inv*s_am[lane+64];
            float ws = w0 + w1;
            #pragma unroll
            for (int o=32;o>0;o>>=1) ws += __shfl_xor(ws,o);
            s_wp[wv][lane] = w0; s_wp[wv][lane+64] = w1;
            if (tid == 0) s_wsm = ws;
            // ---- wc[d] = sum_l w[l]*cur[l][d]  (d = tid, own wave's w copy) ----
            if (tid < D_){
                float acc = 0.f;
                #pragma unroll 16
                for (int l=0; l<L_; l++)
                    acc += s_wp[wv][l] * bu2f(s_cur[l*KC + tid]);
                s_wc[tid] = acc;
            }
        } else {
            // ---- gh GEMV (depends only on s_mf): 600 rows over 256 threads ----
            // unroll-1, no sched_barrier: allow 1-row-deep load pipelining (R14)
            int h = tid - 256;
            #pragma unroll 1
            for (int rr=0; rr<3; rr++){
                int row = h + rr*256;
                if (row < G3D_)
                    s_gh[row] = dot200(WGh + (size_t)row*D_, s_mf);
            }
        }
        __syncthreads();   // #1: s_wc, s_gh, s_wsm ready
        if (tid < D_){
            float acc = dot200(WmtT + (size_t)tid*D_, s_wc);
            s_ctx[tid] = eluf(acc + s_wsm * s_bmt[tid]);
        }
        __syncthreads();   // #2: s_ctx ready
        {
            #pragma unroll 1
            for (int rr=0; rr<2; rr++){
                int row = tid + rr*512;
                if (row < G3D_)
                    s_gi[row] = dot200(WGi + (size_t)row*D_, s_ctx);
            }
        }
        __syncthreads();   // #3: s_gi ready
        if (tid < D_){
            int d = tid;
            float rr = sigmf(s_gi[d] + s_bi[d] + s_gh[d] + s_bh[d]);
            float zz = sigmf(s_gi[D_+d] + s_bi[D_+d] + s_gh[D_+d] + s_bh[D_+d]);
            float nn = tanhf(s_gi[2*D_+d] + s_bi[2*D_+d] + rr*(s_gh[2*D_+d] + s_bh[2*D_+d]));
            float nm = (1.f-zz)*nn + zz*s_mf[d];
            s_mf[d] = nm; s_act[d] = fmaxf(nm, 0.f);
        }
        __syncthreads();   // #4: s_mf/s_act for next t (or epilogue)
        __builtin_amdgcn_sched_barrier(0);           // no cross-t pipelining
    }
    const float dd = (float)(R_ - 2);
    if (tid < 2*D_) s_mf2[tid] = (tid < D_) ? s_mf[tid] : s_mf[tid - D_] + dd;
    __syncthreads();
    float p2 = 0.f;
    if (tid < D_){
        const uint4* wp = (const uint4*)(WmeT + (size_t)tid*400);
        float a0=0.f, a1=0.f;
        #pragma unroll
        for (int kk=0; kk<50; kk++){
            uint4 u = wp[kk];
            f32x4 wA = *(const f32x4*)&s_mf2[8*kk];
            f32x4 wB = *(const f32x4*)&s_mf2[8*kk+4];
            a0 += wA[0]*lo2f(u.x) + wA[1]*hi2f(u.x);
            a1 += wA[2]*lo2f(u.y) + wA[3]*hi2f(u.y);
            a0 += wB[0]*lo2f(u.z) + wB[1]*hi2f(u.z);
            a1 += wB[2]*lo2f(u.w) + wB[3]*hi2f(u.w);
        }
        p2 = (a0 + a1 + bme[tid]) * Wout[tid];
    }
    float o = brSum(p2, s_red);
    if (tid==0){
        o += bout[0];
        if (*amtag == FP32TAG) ((float*)out)[b] = o;
        else ((bf16*)out)[b] = __float2bfloat16(o);
    }
}

extern "C" void kernel_launch(void* const* d_in, const int* in_sizes, int n_in,
                              void* d_out, int out_size, void* d_ws, size_t ws_size,
                              hipStream_t stream) {
    const int* adl = (const int*)d_in[2];
    const int* bdl = (const int*)d_in[3];
    const unsigned* amtag = (const unsigned*)d_in[4];

    static const int srcidx[NSEG] = {4,9,10,12,15,16,17,18,20,23,24,26,27,28};
    static const int segsz[NSEG]  = {16384,1200,3,600,1800,1800,400,1,200,600,600,200,200,1};
    CvtArgs ca;
    int ofs[NSEG+1]; ofs[0] = 0;
    for (int i=0;i<NSEG;i++){ ca.src[i] = d_in[srcidx[i]]; ca.ofs[i] = ofs[i]; ofs[i+1] = ofs[i] + segsz[i]; }
    ca.ofs[NSEG] = ofs[NSEG];   // 23989

    // ws layout. ~54 MB total.
    float* ws   = (float*)d_ws;
    float* conv = ws;                                            // 24000 fl
    unsigned short* XH    = (unsigned short*)(conv + 24000);     // BL_*KP sh
    unsigned short* B2t   = XH + (size_t)BL_*KP;                 // PREPB_N sh
    unsigned short* WatT  = B2t + PREPB_N;                       // PREPW_N sh
    unsigned short* WGi   = WatT + PREPW_N;                      // PREPM_N sh
    unsigned short* WGh   = WGi + PREPM_N;                       // PREPM_N sh
    unsigned short* WmtT  = WGh + PREPM_N;                       // PREPT_N sh
    unsigned short* WmeT  = WmtT + PREPT_N;                      // PREPE_N sh
    unsigned short* Bi16  = WmeT + PREPE_N;                      // BI_N sh
    unsigned short* cur16 = Bi16 + BI_N;                         // BL_*KC sh
    unsigned short* creg  = cur16 + (size_t)BL_*KC;              // C region: BL_*NP sh
    unsigned short* C = creg;
    unsigned short* A16  = creg;                                 // overlay (dead before wnei)
    unsigned short* wnei = creg;                                 // BL_*KC sh overlay
    unsigned short* Q16  = creg + (size_t)BL_*KC;                // B_*MB_*D_ sh overlay
    unsigned short* P16  = Q16 + (size_t)B_*MB_*D_;              // BL_*D_ sh overlay
    float* s1     = (float*)(creg + (size_t)BL_*NP);
    float* tb     = s1 + BL_;
    float* wsum   = tb + BL_;
    float* curdot = wsum + BL_;

    const float* c_amask = conv + ofs[0];
    const float* c_Walign= conv + ofs[1];
    const float* c_balign= conv + ofs[2];
    const float* c_batt  = conv + ofs[3];
    const float* c_bih   = conv + ofs[4];
    const float* c_bhh   = conv + ofs[5];
    const float* c_Wma   = conv + ofs[6];
    const float* c_bma   = conv + ofs[7];
    const float* c_bmt   = conv + ofs[8];
    const float* c_mbih  = conv + ofs[9];
    const float* c_mbhh  = conv + ofs[10];
    const float* c_bme   = conv + ofs[11];
    const float* c_Wout  = conv + ofs[12];
    const float* c_bout  = conv + ofs[13];

    PrepArgs A;
    A.cvt = ca;
    A.Wih = d_in[13]; A.Whh = d_in[14]; A.Watt = d_in[11];
    A.mWih = d_in[21]; A.mWhh = d_in[22]; A.Wmt = d_in[19]; A.Wme = d_in[25];
    A.bond = d_in[1]; A.Wnei = d_in[7]; A.atom = d_in[0]; A.Watom = d_in[5];
    A.conv = conv;
    A.B2t = B2t; A.WatT = WatT; A.WGi = WGi; A.WGh = WGh; A.WmtT = WmtT; A.WmeT = WmeT;
    A.XH = XH; A.A16 = A16; A.Bi16 = Bi16;
    A.amtag = amtag;
    A.ew_total = CONV_N + PREPB_N + PREPW_N + PREPG_N + PREPT_N + PREPE_N
               + XHPAD_N + A_N + BI_N;   // 5110773

    k_prep<<<(A.ew_total + 255)/256, 256, 0, stream>>>(A);
    k_initmm<<<(AROWS/128)*7, 256, 0, stream>>>(A16, Bi16, d_in[6], d_in[8],
                                                XH, P16, Q16, amtag);

    for (int r=0; r<R_; r++){
        k_attn<<<BL_/4, 256, 0, stream>>>(cur16, XH, s1, tb, adl, bdl, P16, Q16,
                                          c_Walign, c_balign, r, wnei, wsum);
        k_ctxmfma<<<(BL_/64)*(NC/64), 256, 0, stream>>>(wnei, wsum, WatT, c_batt, r, XH);
        k_gemm<<<(BL_/64)*NT2, 256, 0, stream>>>(XH, B2t, C, r);
        k_gru2<<<BL_/4, 256, 0, stream>>>(C, XH, cur16, c_bih, c_bhh,
                                          c_Walign, c_Wma, r, s1, tb, curdot);
    }

    k_mol<<<B_, 512, 0, stream>>>(cur16, curdot, c_amask, c_Wma, c_bma, WmtT, c_bmt,
                                  WGi, WGh, c_mbih, c_mbhh, WmeT, c_bme, c_Wout, c_bout,
                                  d_out, amtag);
}